// Round 23
// baseline (852.597 us; speedup 1.0000x reference)
//
#include <hip/hip_runtime.h>
#include <hip/hip_bf16.h>
#include <math.h>

typedef unsigned short u16;
typedef unsigned int u32;
typedef __bf16 bf16v8 __attribute__((ext_vector_type(8)));
typedef _Float16 f16v8 __attribute__((ext_vector_type(8)));
typedef __attribute__((ext_vector_type(4))) float f32x4;

#define D_MOD 256
#define NHEAD 8
#define DHEAD 32
#define SEQL 97
#define NTOKE 23

__device__ __forceinline__ float bf2f(u16 u){
  union { unsigned int i; float f; } x; x.i = ((unsigned int)u) << 16; return x.f;
}
__device__ __forceinline__ u16 f2bf(float f){
  return __builtin_bit_cast(u16, (__bf16)f);
}
__device__ __forceinline__ float gelu_fast(float v){
  float z = v * 0.70710678118654752f;
  float az = fabsf(z);
  float t = __builtin_amdgcn_rcpf(fmaf(0.3275911f, az, 1.0f));
  float p = t*(0.254829592f + t*(-0.284496736f + t*(1.421413741f + t*(-1.453152027f + t*1.061405429f))));
  float e = __expf(-z*z);
  float y = 1.0f - p*e;
  float erfz = copysignf(y, z);
  return 0.5f * v * (1.0f + erfz);
}
__device__ __forceinline__ void gld16(const void* g, void* l){
  __builtin_amdgcn_global_load_lds((const __attribute__((address_space(1))) void*)g,
                                   (__attribute__((address_space(3))) void*)l, 16, 0, 0);
}

// ---------- ONE-SHOT weight prep (r19-exact): transpose + event fragment-packing
__global__ __launch_bounds__(256) void prep_all(
    const float* __restrict__ aw, const float* __restrict__ ew,
    const float* __restrict__ f1m, const float* __restrict__ f2m,
    const float* __restrict__ f1e, const float* __restrict__ f2e,
    const float* __restrict__ gw2,
    u16* __restrict__ modWT, u16* __restrict__ evtWT,
    u16* __restrict__ modF1T, u16* __restrict__ modF2T,
    u16* __restrict__ evtF1T, u16* __restrict__ evtF2T,
    u16* __restrict__ globW2T,
    u16* __restrict__ WP, u16* __restrict__ F1P, u16* __restrict__ F2P)
{
  const int id = blockIdx.x;
  const float* src; u16* dst; u16* pk = nullptr; int K, N, kx, nx, t; long sS, dS;
  if (id < 512)      { t = id;        src = aw;  dst = modWT;   K=256;  N=256;  kx=8;  nx=8;  sS=65536;  dS=65536;  }
  else if (id < 1280){ t = id - 512;  src = ew;  dst = evtWT;   K=256;  N=256;  kx=8;  nx=8;  sS=65536;  dS=65536;  pk = WP;  }
  else if (id < 1792){ t = id - 1280; src = f1m; dst = modF1T;  K=256;  N=1024; kx=8;  nx=32; sS=262144; dS=262144; }
  else if (id < 2304){ t = id - 1792; src = f2m; dst = modF2T;  K=1024; N=256;  kx=32; nx=8;  sS=262144; dS=262144; }
  else if (id < 3840){ t = id - 2304; src = f1e; dst = evtF1T;  K=256;  N=2048; kx=8;  nx=64; sS=524288; dS=524288; pk = F1P; }
  else if (id < 5376){ t = id - 3840; src = f2e; dst = evtF2T;  K=2048; N=256;  kx=64; nx=8;  sS=524288; dS=524288; pk = F2P; }
  else               { t = id - 5376; src = gw2; dst = globW2T; K=256;  N=256;  kx=8;  nx=8;  sS=65536;  dS=65536;  }
  const int per = kx * nx;
  const int z = t / per, rem = t % per;
  const int k0 = (rem % kx) * 32, n0 = (rem / kx) * 32;
  src += (long)z * sS; dst += (long)z * dS;
  __shared__ float tt[32][33];
  const int tx = threadIdx.x & 31, ty = threadIdx.x >> 5;
  #pragma unroll
  for (int r = ty; r < 32; r += 8)
    tt[r][tx] = src[(long)(k0 + r) * N + n0 + tx];
  __syncthreads();
  #pragma unroll
  for (int r = ty; r < 32; r += 8)
    dst[(long)(n0 + r) * K + k0 + tx] = f2bf(tt[tx][r]);
  if (pk && threadIdx.x < 128){
    const int q = threadIdx.x >> 6, l = threadIdx.x & 63;
    const int nb = (n0 >> 4) + q, kb = k0 >> 5;
    const int c = q*16 + (l & 15);
    const int klb = (l >> 4) * 8;
    const long fragi = (long)nb * (K/32) + kb;
    u16 frag[8];
    #pragma unroll
    for (int e = 0; e < 8; e++) frag[e] = f2bf(tt[klb + e][c]);
    u16* d = pk + (long)z * (long)N * K + (fragi*64 + l)*8;
    *(uint4*)d = *(const uint4*)frag;
  }
}

// ---------- counts / scan / scatter
__global__ void count_k(const int* __restrict__ bids, int* __restrict__ counts, int n){
  int i = blockIdx.x * blockDim.x + threadIdx.x;
  if (i < n) atomicAdd(&counts[bids[i]], 1);
}

__global__ void scan_k(const int* __restrict__ counts, int* __restrict__ starts, int M){
  __shared__ int buf[1024];
  int t = threadIdx.x;
  int v = (t < M) ? counts[t] : 0;
  buf[t] = v;
  __syncthreads();
  for (int o = 1; o < 1024; o <<= 1){
    int x = (t >= o) ? buf[t - o] : 0;
    __syncthreads();
    buf[t] += x;
    __syncthreads();
  }
  if (t < M) starts[t] = buf[t] - v;
}

__global__ __launch_bounds__(64) void cls_fill(u16* __restrict__ seqc, const float* __restrict__ cls_mod,
                                               const int* __restrict__ starts){
  int m = blockIdx.x, t = threadIdx.x;
  long row = (long)starts[m] + m;
  const float4 v = *(const float4*)(cls_mod + t * 4);
  u16* d = seqc + row * D_MOD + t * 4;
  d[0] = f2bf(v.x); d[1] = f2bf(v.y); d[2] = f2bf(v.z); d[3] = f2bf(v.w);
}

__global__ __launch_bounds__(64) void scatter_k(const float* __restrict__ feats, const float* __restrict__ coords,
                          const int* __restrict__ bids, u16* __restrict__ seqc, float* __restrict__ scc){
  int i = blockIdx.x, t = threadIdx.x;
  long row = (long)i + bids[i] + 1;
  const float4 v = *(const float4*)(feats + (long)i * D_MOD + t * 4);
  u16* d = seqc + row * D_MOD + t * 4;
  d[0] = f2bf(v.x); d[1] = f2bf(v.y); d[2] = f2bf(v.z); d[3] = f2bf(v.w);
  if (t < 3) scc[row * 3 + t] = coords[(long)i * 3 + t];
}

// ---------- 256x128 bf16 MFMA GEMM, BK=64, 8 waves (r20-exact; 48KB LDS -> 3 blocks/CU)
template<int EPI> // 0 none, 1 gelu, 2 relu, 3 +resid
__global__ __launch_bounds__(512) void gemm256(
    const u16* __restrict__ A, const u16* __restrict__ Wt,
    const float* __restrict__ bias, const u16* __restrict__ resid,
    u16* __restrict__ C, int K, int N)
{
  __shared__ char smemraw[49152];          // As [2][256][32]=32KB + Bs [2][128][32]=16KB
  u16* As = (u16*)smemraw;
  u16* Bs = (u16*)(smemraw + 32768);
  float* stg = (float*)smemraw;            // epilogue [32][132] f32 (16.9KB, aliases As)

  const int tid = threadIdx.x;
  const int w = tid >> 6, l = tid & 63;
  const int wr = w >> 1, wc = w & 1;

  const long nwg = (long)gridDim.x * gridDim.y;
  const long orig = (long)blockIdx.y * gridDim.x + blockIdx.x;
  const long q = nwg >> 3, r = nwg & 7;
  const long xcd = orig & 7, idx = orig >> 3;
  const long swz = (xcd < r ? xcd * (q + 1) : r * (q + 1) + (xcd - r) * q) + idx;
  const int colb = (int)(swz % gridDim.x);
  const long rowb = swz / gridDim.x;
  const long row0 = rowb * 256;
  const int col0 = colb * 128;

  const int fr = l & 15;
  const int ko = (l >> 4) * 8;
  f32x4 acc[4][4] = {};

  for (int kt = 0; kt < K; kt += 64){
    __syncthreads();
    #pragma unroll
    for (int p = 0; p < 4; p++){           // A: 2048 slots of 16B
      const int s = p * 512 + tid;
      const int inner = s & 1023, half = s >> 10;
      gld16(A + (row0 + (inner >> 2)) * K + kt + half*32 + (inner & 3)*8,
            As + (p*512 + w*64) * 8);
    }
    #pragma unroll
    for (int p = 0; p < 2; p++){           // B: 1024 slots of 16B
      const int s = p * 512 + tid;
      const int inner = s & 511, half = s >> 9;
      gld16(Wt + (long)(col0 + (inner >> 2)) * K + kt + half*32 + (inner & 3)*8,
            Bs + (p*512 + w*64) * 8);
    }
    __syncthreads();
    #pragma unroll
    for (int kk2 = 0; kk2 < 2; kk2++){
      bf16v8 af[4], bfv[4];
      #pragma unroll
      for (int mi = 0; mi < 4; mi++)
        af[mi] = __builtin_bit_cast(bf16v8, *(const uint4*)(As + kk2*8192 + (wr*64 + mi*16 + fr)*32 + ko));
      #pragma unroll
      for (int ni = 0; ni < 4; ni++)
        bfv[ni] = __builtin_bit_cast(bf16v8, *(const uint4*)(Bs + kk2*4096 + (wc*64 + ni*16 + fr)*32 + ko));
      #pragma unroll
      for (int mi = 0; mi < 4; mi++)
        #pragma unroll
        for (int ni = 0; ni < 4; ni++)
          acc[mi][ni] = __builtin_amdgcn_mfma_f32_16x16x32_bf16(af[mi], bfv[ni], acc[mi][ni], 0, 0, 0);
    }
  }

  // ---- epilogue: 8 passes of 32 rows; staged f32 -> coalesced dwordx4 stores
  const int rq = (l >> 4) * 4;
  #pragma unroll
  for (int p = 0; p < 8; p++){
    __syncthreads();
    if (wr == (p >> 1)){
      #pragma unroll
      for (int mm = 0; mm < 2; mm++){
        const int mi = (p & 1) * 2 + mm;
        #pragma unroll
        for (int ni = 0; ni < 4; ni++){
          const int coll = wc*64 + ni*16 + fr;
          const float bb = bias[col0 + coll];
          #pragma unroll
          for (int j = 0; j < 4; j++){
            float v = acc[mi][ni][j] + bb;
            if (EPI == 1) v = gelu_fast(v);
            if (EPI == 2) v = fmaxf(v, 0.0f);
            stg[(mm*16 + rq + j) * 132 + coll] = v;
          }
        }
      }
    }
    __syncthreads();
    {
      const int rowl = tid >> 4;           // 512 slots: 32 rows x 16 col8
      const int cs = (tid & 15) * 8;
      const long gbase = (row0 + p*32 + rowl) * (long)N + col0 + cs;
      float4 lo = *(const float4*)(stg + rowl*132 + cs);
      float4 hi = *(const float4*)(stg + rowl*132 + cs + 4);
      float vv[8] = {lo.x, lo.y, lo.z, lo.w, hi.x, hi.y, hi.z, hi.w};
      if (EPI == 3){
        uint4 rv = *(const uint4*)(resid + gbase);
        const u16* rp = (const u16*)&rv;
        #pragma unroll
        for (int e = 0; e < 8; e++) vv[e] += bf2f(rp[e]);
      }
      uint4 ov;
      u16* op = (u16*)&ov;
      #pragma unroll
      for (int e = 0; e < 8; e++) op[e] = f2bf(vv[e]);
      *(uint4*)(C + gbase) = ov;
    }
  }
}

// ---------- 128x256 bf16 MFMA GEMM + residual + LayerNorm fused epilogue.
// N fixed = 256 (full row in-block). Same per-wave geometry (64x64, acc[4][4]),
// same 48KB LDS (As 16KB + Bs 32KB -> 3 blocks/CU), same K accumulation order.
__global__ __launch_bounds__(512) void gemm_ln(
    const u16* __restrict__ A, const u16* __restrict__ Wt,
    const float* __restrict__ bias, const u16* __restrict__ resid,
    u16* __restrict__ C, int K,
    const float* __restrict__ lnS, const float* __restrict__ lnB)
{
  __shared__ char smemraw[49152];          // As [2][128][32]=16KB + Bs [2][256][32]=32KB
  u16* As = (u16*)smemraw;
  u16* Bs = (u16*)(smemraw + 16384);
  float* stg = (float*)smemraw;            // epilogue [32][260] f32 (33.3KB, aliases)

  const int tid = threadIdx.x;
  const int w = tid >> 6, l = tid & 63;
  const int wr = w >> 2, wc = w & 3;       // wr 0..1 (64-row group), wc 0..3 (64-col group)

  const long nwg = gridDim.y;              // gridDim.x == 1
  const long orig = blockIdx.y;
  const long q = nwg >> 3, r = nwg & 7;
  const long xcd = orig & 7, idx = orig >> 3;
  const long swz = (xcd < r ? xcd * (q + 1) : r * (q + 1) + (xcd - r) * q) + idx;
  const long row0 = swz * 128;

  const int fr = l & 15;
  const int ko = (l >> 4) * 8;
  f32x4 acc[4][4] = {};

  for (int kt = 0; kt < K; kt += 64){
    __syncthreads();
    #pragma unroll
    for (int p = 0; p < 2; p++){           // A: 1024 slots of 16B
      const int s = p * 512 + tid;
      const int inner = s & 511, half = s >> 9;
      gld16(A + (row0 + (inner >> 2)) * K + kt + half*32 + (inner & 3)*8,
            As + (p*512 + w*64) * 8);
    }
    #pragma unroll
    for (int p = 0; p < 4; p++){           // B: 2048 slots of 16B (all 256 N-rows)
      const int s = p * 512 + tid;
      const int inner = s & 1023, half = s >> 10;
      gld16(Wt + (long)(inner >> 2) * K + kt + half*32 + (inner & 3)*8,
            Bs + (p*512 + w*64) * 8);
    }
    __syncthreads();
    #pragma unroll
    for (int kk2 = 0; kk2 < 2; kk2++){
      bf16v8 af[4], bfv[4];
      #pragma unroll
      for (int mi = 0; mi < 4; mi++)
        af[mi] = __builtin_bit_cast(bf16v8, *(const uint4*)(As + kk2*4096 + (wr*64 + mi*16 + fr)*32 + ko));
      #pragma unroll
      for (int ni = 0; ni < 4; ni++)
        bfv[ni] = __builtin_bit_cast(bf16v8, *(const uint4*)(Bs + kk2*8192 + (wc*64 + ni*16 + fr)*32 + ko));
      #pragma unroll
      for (int mi = 0; mi < 4; mi++)
        #pragma unroll
        for (int ni = 0; ni < 4; ni++)
          acc[mi][ni] = __builtin_amdgcn_mfma_f32_16x16x32_bf16(af[mi], bfv[ni], acc[mi][ni], 0, 0, 0);
    }
  }

  // ---- epilogue: 4 passes of 32 rows; full 256-col row staged -> +resid -> LN -> bf16
  const int rq = (l >> 4) * 4;
  #pragma unroll
  for (int p = 0; p < 4; p++){
    __syncthreads();
    if (wr == (p >> 1)){
      #pragma unroll
      for (int mm = 0; mm < 2; mm++){
        const int mi = (p & 1) * 2 + mm;
        #pragma unroll
        for (int ni = 0; ni < 4; ni++){
          const int coll = wc*64 + ni*16 + fr;
          const float bb = bias[coll];
          #pragma unroll
          for (int j = 0; j < 4; j++)
            stg[(mm*16 + rq + j) * 260 + coll] = acc[mi][ni][j] + bb;
        }
      }
    }
    __syncthreads();
    {
      const int rowl = tid >> 4;           // 32 rows x 16 threads/row
      const int c0 = (tid & 15) * 16;
      const long gbase = (row0 + p*32 + rowl) * 256 + c0;
      float v[16];
      uint4 r0 = *(const uint4*)(resid + gbase);
      uint4 r1 = *(const uint4*)(resid + gbase + 8);
      const u16* rp0 = (const u16*)&r0;
      const u16* rp1 = (const u16*)&r1;
      #pragma unroll
      for (int e = 0; e < 8; e++){
        v[e]     = stg[rowl*260 + c0 + e]     + bf2f(rp0[e]);
        v[8 + e] = stg[rowl*260 + c0 + 8 + e] + bf2f(rp1[e]);
      }
      float sum = 0.f, sq = 0.f;
      #pragma unroll
      for (int e = 0; e < 16; e++){ sum += v[e]; sq += v[e]*v[e]; }
      #pragma unroll
      for (int o = 1; o < 16; o <<= 1){
        sum += __shfl_xor(sum, o);
        sq  += __shfl_xor(sq,  o);
      }
      const float mu = sum * (1.0f/256.0f);
      const float var = sq * (1.0f/256.0f) - mu*mu;
      const float rs = rsqrtf(var + 1e-5f);
      uint4 o0, o1;
      u16* op0 = (u16*)&o0; u16* op1 = (u16*)&o1;
      #pragma unroll
      for (int e = 0; e < 8; e++){
        op0[e] = f2bf((v[e]     - mu) * rs * lnS[c0 + e]     + lnB[c0 + e]);
        op1[e] = f2bf((v[8 + e] - mu) * rs * lnS[c0 + 8 + e] + lnB[c0 + 8 + e]);
      }
      *(uint4*)(C + gbase)     = o0;
      *(uint4*)(C + gbase + 8) = o1;
    }
  }
}

// ---------- module attention body (r9-exact math), NT = #16-key-tiles, static bounds
template<int NT>
__device__ __forceinline__ void attn_body(
    char* __restrict__ smemRaw,
    const u16* __restrict__ qkv, const float* __restrict__ scc,
    const float* __restrict__ rel, const int S, const long base,
    u16* __restrict__ out)
{
  constexpr int KS  = (NT + 1) / 2;
  constexpr int NK  = NT * 16;
  constexpr int STR = (KS * 32 <= 64) ? 64 : 128;
  constexpr int PBYTES = (NK * STR * 2 > NK * 132) ? NK * STR * 2 : NK * 132;
  u16* Pb = (u16*)smemRaw;
  u16* Vt = (u16*)(smemRaw + PBYTES);
  float* pj = (float*)(smemRaw + PBYTES + 32 * STR * 2);

  const int h = blockIdx.y;
  const int tid = threadIdx.x, w = tid >> 6, l = tid & 63;
  const int fr = l & 15, ko = (l >> 4) * 8;

  if (tid < NK){
    float v = 1e30f;
    if (tid < S){
      const float* s3 = scc + (base + tid) * 3;
      v = s3[0]*rel[h*3] + s3[1]*rel[h*3+1] + s3[2]*rel[h*3+2];
    }
    pj[tid] = v;
  }
  for (int idx = tid; idx < NK*32; idx += 256){
    int key = idx >> 5, d = idx & 31;
    float v = bf2f(qkv[(base + key)*768 + 512 + h*32 + d]);
    v = fminf(fmaxf(v, -60000.0f), 60000.0f);
    _Float16 hv = (_Float16)v;
    Vt[d*STR + (key ^ ((d & 7) << 3))] = __builtin_bit_cast(u16, hv);
  }
  for (int idx = tid; idx < 32*16; idx += 256){
    int d = idx >> 4, c = NK + (idx & 15);
    Vt[d*STR + (c ^ ((d & 7) << 3))] = 0;
  }
  for (int idx = tid; idx < NK*16; idx += 256){
    int row = idx >> 4, c = NK + (idx & 15);
    Pb[row*STR + (c ^ ((row & 7) << 3))] = 0;
  }
  __syncthreads();

  f32x4 accs[2][NT];
  bf16v8 kf[NT];
  #pragma unroll
  for (int nt = 0; nt < NT; nt++)
    kf[nt] = __builtin_bit_cast(bf16v8, *(const uint4*)(qkv + (base + nt*16 + fr)*768 + 256 + h*32 + ko));
  #pragma unroll
  for (int rr2 = 0; rr2 < 2; rr2++){
    const int rt = w + rr2*4;
    if (rt > NT - 1) break;
    bf16v8 qf = __builtin_bit_cast(bf16v8, *(const uint4*)(qkv + (base + rt*16 + fr)*768 + h*32 + ko));
    #pragma unroll
    for (int nt = 0; nt < NT; nt++){
      f32x4 z = {0.f, 0.f, 0.f, 0.f};
      accs[rr2][nt] = __builtin_amdgcn_mfma_f32_16x16x32_bf16(qf, kf[nt], z, 0, 0, 0);
    }
  }

  float pjr[NT];
  #pragma unroll
  for (int nt = 0; nt < NT; nt++) pjr[nt] = pj[nt*16 + fr];
  const float SCALE = 0.17677669529663687f;
  #pragma unroll
  for (int rr2 = 0; rr2 < 2; rr2++){
    const int rt = w + rr2*4;
    if (rt > NT - 1) break;
    #pragma unroll
    for (int j = 0; j < 4; j++){
      float x[NT], mx = -1e30f;
      #pragma unroll
      for (int nt = 0; nt < NT; nt++){
        x[nt] = accs[rr2][nt][j] * SCALE - pjr[nt];
        mx = fmaxf(mx, x[nt]);
      }
      #pragma unroll
      for (int o = 1; o < 16; o <<= 1) mx = fmaxf(mx, __shfl_xor(mx, o));
      float sum = 0.f;
      #pragma unroll
      for (int nt = 0; nt < NT; nt++){
        x[nt] = __expf(x[nt] - mx);
        sum += x[nt];
      }
      #pragma unroll
      for (int o = 1; o < 16; o <<= 1) sum += __shfl_xor(sum, o);
      const float inv = 1.0f / sum;
      const int row = rt*16 + (l >> 4)*4 + j;
      #pragma unroll
      for (int nt = 0; nt < NT; nt++){
        _Float16 hp = (_Float16)(x[nt] * inv);
        Pb[row*STR + ((nt*16 + fr) ^ ((row & 7) << 3))] = __builtin_bit_cast(u16, hp);
      }
    }
  }
  __syncthreads();

  f32x4 accO[2][2];
  #pragma unroll
  for (int rr2 = 0; rr2 < 2; rr2++){
    const int rt = w + rr2*4;
    if (rt > NT - 1) break;
    #pragma unroll
    for (int nt = 0; nt < 2; nt++){
      f32x4 z = {0.f, 0.f, 0.f, 0.f};
      accO[rr2][nt] = z;
    }
    #pragma unroll
    for (int ks = 0; ks < KS; ks++){
      const int prow = rt*16 + fr;
      f16v8 pa = __builtin_bit_cast(f16v8, *(const uint4*)(Pb + prow*STR + ((ks*32 + ko) ^ ((prow & 7) << 3))));
      #pragma unroll
      for (int nt = 0; nt < 2; nt++){
        const int vrow = nt*16 + fr;
        f16v8 vb = __builtin_bit_cast(f16v8, *(const uint4*)(Vt + vrow*STR + ((ks*32 + ko) ^ ((vrow & 7) << 3))));
        accO[rr2][nt] = __builtin_amdgcn_mfma_f32_16x16x32_f16(pa, vb, accO[rr2][nt], 0, 0, 0);
      }
    }
  }
  __syncthreads();

  float* O = (float*)smemRaw;
  #pragma unroll
  for (int rr2 = 0; rr2 < 2; rr2++){
    const int rt = w + rr2*4;
    if (rt > NT - 1) break;
    #pragma unroll
    for (int nt = 0; nt < 2; nt++)
      #pragma unroll
      for (int j = 0; j < 4; j++)
        O[(rt*16 + (l>>4)*4 + j)*33 + nt*16 + fr] = accO[rr2][nt][j];
  }
  __syncthreads();
  for (int idx = tid; idx < NK*16; idx += 256){
    const int row = idx >> 4;
    if (row >= S) continue;
    const int c = (idx & 15) * 2;
    const float f0 = O[row*33 + c], f1 = O[row*33 + c + 1];
    u32 pk = (u32)f2bf(f0) | ((u32)f2bf(f1) << 16);
    *(u32*)(out + (base + row)*256 + h*32 + c) = pk;
  }
}

// ---------- single-launch bucketed attention
__global__ __launch_bounds__(256) void mod_attn_all(
    const u16* __restrict__ qkv, const float* __restrict__ scc,
    const float* __restrict__ rel, const int* __restrict__ counts,
    const int* __restrict__ starts, u16* __restrict__ out)
{
  __shared__ __align__(16) char smem[37376];
  const int m = blockIdx.x;
  const int S = counts[m] + 1;
  const long base = (long)starts[m] + m;
  if (S <= 48)      attn_body<3>(smem, qkv, scc, rel, S, base, out);
  else if (S <= 80) attn_body<5>(smem, qkv, scc, rel, S, base, out);
  else              attn_body<7>(smem, qkv, scc, rel, S, base, out);
}

// ---------- FUSED 3-layer event transformer (r19-exact: packed weights + setprio)
__global__ __launch_bounds__(512, 1) void evt_fused(
    u16* __restrict__ se,
    const u16* __restrict__ attnWP, const float* __restrict__ attnB,
    const u16* __restrict__ f1P, const float* __restrict__ f1B,
    const u16* __restrict__ f2P, const float* __restrict__ f2B,
    const float* __restrict__ lnS, const float* __restrict__ lnB)
{
  __shared__ u16 X[32*264];
  __shared__ u16 Yb[2*32*264];
  __shared__ u16 Sb[8*32*40];
  __shared__ float st1[32*8], st2[32*8];
  __shared__ float muA[32], rsA[32];

  const int b = blockIdx.x;
  const int tid = threadIdx.x, w = tid >> 6, l = tid & 63;
  const int fr = l & 15, hi4 = (l >> 4) * 4, ko = (l >> 4) * 8;
  const long tb = (long)b * NTOKE;
  u16* Sw = Sb + w * 1280;
  u16* Y = Yb;

  for (int idx = tid; idx < 736; idx += 512){
    const int row = idx >> 5, c8 = (idx & 31) * 8;
    *(uint4*)&X[row*264 + c8] = *(const uint4*)(se + (tb + row)*256 + c8);
  }
  for (int idx = tid; idx < 288; idx += 512){
    const int row = 23 + (idx >> 5), c8 = (idx & 31) * 8;
    uint4 z = {0,0,0,0};
    *(uint4*)&X[row*264 + c8] = z;
  }
  __syncthreads();

  for (int lay = 0; lay < 3; lay++){
    const u16*  WlP = attnWP + (long)lay * 4 * 65536;
    const float* Bl = attnB + lay * 1024;
    const u16*  F1  = f1P + (long)lay * 524288;
    const u16*  F2  = f2P + (long)lay * 524288;

    bf16v8 qf[2], kf[2], pa[2];
    {
      bf16v8 wr_[8][2];
      #pragma unroll
      for (int ks = 0; ks < 8; ks++)
        #pragma unroll
        for (int ct = 0; ct < 2; ct++)
          wr_[ks][ct] = __builtin_bit_cast(bf16v8, *(const uint4*)(WlP + ((w*2+ct)*8 + ks)*512 + l*8));
      f32x4 acc[2][2] = {};
      __builtin_amdgcn_s_setprio(1);
      #pragma unroll
      for (int ks = 0; ks < 8; ks++){
        bf16v8 a0 = __builtin_bit_cast(bf16v8, *(const uint4*)&X[fr*264 + ks*32 + ko]);
        bf16v8 a1 = __builtin_bit_cast(bf16v8, *(const uint4*)&X[(16+fr)*264 + ks*32 + ko]);
        #pragma unroll
        for (int ct = 0; ct < 2; ct++){
          acc[0][ct] = __builtin_amdgcn_mfma_f32_16x16x32_bf16(a0, wr_[ks][ct], acc[0][ct], 0, 0, 0);
          acc[1][ct] = __builtin_amdgcn_mfma_f32_16x16x32_bf16(a1, wr_[ks][ct], acc[1][ct], 0, 0, 0);
        }
      }
      __builtin_amdgcn_s_setprio(0);
      #pragma unroll
      for (int rt = 0; rt < 2; rt++)
        #pragma unroll
        for (int ct = 0; ct < 2; ct++){
          const float bb = Bl[w*32 + ct*16 + fr];
          #pragma unroll
          for (int j = 0; j < 4; j++)
            Sw[(rt*16 + hi4 + j)*40 + ct*16 + fr] = f2bf(acc[rt][ct][j] + bb);
        }
      qf[0] = __builtin_bit_cast(bf16v8, *(const uint4*)&Sw[fr*40 + ko]);
      qf[1] = __builtin_bit_cast(bf16v8, *(const uint4*)&Sw[(16+fr)*40 + ko]);
    }
    {
      bf16v8 wr_[8][2];
      #pragma unroll
      for (int ks = 0; ks < 8; ks++)
        #pragma unroll
        for (int ct = 0; ct < 2; ct++)
          wr_[ks][ct] = __builtin_bit_cast(bf16v8, *(const uint4*)(WlP + 65536 + ((w*2+ct)*8 + ks)*512 + l*8));
      f32x4 acc[2][2] = {};
      __builtin_amdgcn_s_setprio(1);
      #pragma unroll
      for (int ks = 0; ks < 8; ks++){
        bf16v8 a0 = __builtin_bit_cast(bf16v8, *(const uint4*)&X[fr*264 + ks*32 + ko]);
        bf16v8 a1 = __builtin_bit_cast(bf16v8, *(const uint4*)&X[(16+fr)*264 + ks*32 + ko]);
        #pragma unroll
        for (int ct = 0; ct < 2; ct++){
          acc[0][ct] = __builtin_amdgcn_mfma_f32_16x16x32_bf16(a0, wr_[ks][ct], acc[0][ct], 0, 0, 0);
          acc[1][ct] = __builtin_amdgcn_mfma_f32_16x16x32_bf16(a1, wr_[ks][ct], acc[1][ct], 0, 0, 0);
        }
      }
      __builtin_amdgcn_s_setprio(0);
      #pragma unroll
      for (int rt = 0; rt < 2; rt++)
        #pragma unroll
        for (int ct = 0; ct < 2; ct++){
          const float bb = Bl[256 + w*32 + ct*16 + fr];
          #pragma unroll
          for (int j = 0; j < 4; j++)
            Sw[(rt*16 + hi4 + j)*40 + ct*16 + fr] = f2bf(acc[rt][ct][j] + bb);
        }
      kf[0] = __builtin_bit_cast(bf16v8, *(const uint4*)&Sw[fr*40 + ko]);
      kf[1] = __builtin_bit_cast(bf16v8, *(const uint4*)&Sw[(16+fr)*40 + ko]);
    }
    {
      f32x4 accS[2][2];
      #pragma unroll
      for (int rt = 0; rt < 2; rt++)
        #pragma unroll
        for (int nt = 0; nt < 2; nt++){
          f32x4 z = {0.f,0.f,0.f,0.f};
          accS[rt][nt] = __builtin_amdgcn_mfma_f32_16x16x32_bf16(qf[rt], kf[nt], z, 0, 0, 0);
        }
      const float SCALE = 0.17677669529663687f;
      const bool v1 = (fr < 7);
      #pragma unroll
      for (int rt = 0; rt < 2; rt++){
        #pragma unroll
        for (int j = 0; j < 4; j++){
          float x0 = accS[rt][0][j] * SCALE;
          float x1 = v1 ? accS[rt][1][j] * SCALE : -1e30f;
          float mx = fmaxf(x0, x1);
          #pragma unroll
          for (int o = 1; o < 16; o <<= 1) mx = fmaxf(mx, __shfl_xor(mx, o));
          float e0 = __expf(x0 - mx);
          float e1 = v1 ? __expf(x1 - mx) : 0.0f;
          float sum = e0 + e1;
          #pragma unroll
          for (int o = 1; o < 16; o <<= 1) sum += __shfl_xor(sum, o);
          const float inv = 1.0f / sum;
          const int row = rt*16 + hi4 + j;
          Sw[row*40 + fr]      = f2bf(e0 * inv);
          Sw[row*40 + 16 + fr] = f2bf(e1 * inv);
        }
      }
      pa[0] = __builtin_bit_cast(bf16v8, *(const uint4*)&Sw[fr*40 + ko]);
      pa[1] = __builtin_bit_cast(bf16v8, *(const uint4*)&Sw[(16+fr)*40 + ko]);
    }
    {
      bf16v8 wr_[8][2];
      #pragma unroll
      for (int ks = 0; ks < 8; ks++)
        #pragma unroll
        for (int ct = 0; ct < 2; ct++)
          wr_[ks][ct] = __builtin_bit_cast(bf16v8, *(const uint4*)(WlP + 131072 + ((w*2+ct)*8 + ks)*512 + l*8));
      f32x4 acc[2][2] = {};
      __builtin_amdgcn_s_setprio(1);
      #pragma unroll
      for (int ks = 0; ks < 8; ks++){
        bf16v8 a0 = __builtin_bit_cast(bf16v8, *(const uint4*)&X[fr*264 + ks*32 + ko]);
        bf16v8 a1 = __builtin_bit_cast(bf16v8, *(const uint4*)&X[(16+fr)*264 + ks*32 + ko]);
        #pragma unroll
        for (int ct = 0; ct < 2; ct++){
          acc[0][ct] = __builtin_amdgcn_mfma_f32_16x16x32_bf16(a0, wr_[ks][ct], acc[0][ct], 0, 0, 0);
          acc[1][ct] = __builtin_amdgcn_mfma_f32_16x16x32_bf16(a1, wr_[ks][ct], acc[1][ct], 0, 0, 0);
        }
      }
      __builtin_amdgcn_s_setprio(0);
      #pragma unroll
      for (int rt = 0; rt < 2; rt++)
        #pragma unroll
        for (int ct = 0; ct < 2; ct++){
          const float bb = Bl[512 + w*32 + ct*16 + fr];
          u16* dst = &Sw[(ct*16 + fr)*40 + rt*16 + hi4];
          #pragma unroll
          for (int j = 0; j < 4; j++)
            dst[j] = f2bf(acc[rt][ct][j] + bb);
        }
      bf16v8 vb0 = __builtin_bit_cast(bf16v8, *(const uint4*)&Sw[fr*40 + ko]);
      bf16v8 vb1 = __builtin_bit_cast(bf16v8, *(const uint4*)&Sw[(16+fr)*40 + ko]);
      f32x4 accO[2][2];
      #pragma unroll
      for (int rt = 0; rt < 2; rt++){
        f32x4 z = {0.f,0.f,0.f,0.f};
        accO[rt][0] = __builtin_amdgcn_mfma_f32_16x16x32_bf16(pa[rt], vb0, z, 0, 0, 0);
        accO[rt][1] = __builtin_amdgcn_mfma_f32_16x16x32_bf16(pa[rt], vb1, z, 0, 0, 0);
      }
      #pragma unroll
      for (int rt = 0; rt < 2; rt++)
        #pragma unroll
        for (int nt = 0; nt < 2; nt++)
          #pragma unroll
          for (int j = 0; j < 4; j++)
            Y[(rt*16 + hi4 + j)*264 + w*32 + nt*16 + fr] = f2bf(accO[rt][nt][j]);
    }
    __syncthreads();

    {
      bf16v8 wr_[8][2];
      #pragma unroll
      for (int ks = 0; ks < 8; ks++)
        #pragma unroll
        for (int ct = 0; ct < 2; ct++)
          wr_[ks][ct] = __builtin_bit_cast(bf16v8, *(const uint4*)(WlP + 196608 + ((w*2+ct)*8 + ks)*512 + l*8));
      f32x4 acc[2][2] = {};
      __builtin_amdgcn_s_setprio(1);
      #pragma unroll
      for (int ks = 0; ks < 8; ks++){
        bf16v8 a0 = __builtin_bit_cast(bf16v8, *(const uint4*)&Y[fr*264 + ks*32 + ko]);
        bf16v8 a1 = __builtin_bit_cast(bf16v8, *(const uint4*)&Y[(16+fr)*264 + ks*32 + ko]);
        #pragma unroll
        for (int ct = 0; ct < 2; ct++){
          acc[0][ct] = __builtin_amdgcn_mfma_f32_16x16x32_bf16(a0, wr_[ks][ct], acc[0][ct], 0, 0, 0);
          acc[1][ct] = __builtin_amdgcn_mfma_f32_16x16x32_bf16(a1, wr_[ks][ct], acc[1][ct], 0, 0, 0);
        }
      }
      __builtin_amdgcn_s_setprio(0);
      float val[2][2][4];
      #pragma unroll
      for (int ct = 0; ct < 2; ct++){
        const int col = w*32 + ct*16 + fr;
        const float bb = Bl[768 + col];
        #pragma unroll
        for (int rt = 0; rt < 2; rt++)
          #pragma unroll
          for (int j = 0; j < 4; j++)
            val[rt][ct][j] = acc[rt][ct][j] + bb + bf2f(X[(rt*16 + hi4 + j)*264 + col]);
      }
      #pragma unroll
      for (int rt = 0; rt < 2; rt++)
        #pragma unroll
        for (int j = 0; j < 4; j++){
          float s1 = val[rt][0][j] + val[rt][1][j];
          float s2 = val[rt][0][j]*val[rt][0][j] + val[rt][1][j]*val[rt][1][j];
          #pragma unroll
          for (int o = 1; o < 16; o <<= 1){ s1 += __shfl_xor(s1, o); s2 += __shfl_xor(s2, o); }
          if (fr == 0){
            const int row = rt*16 + hi4 + j;
            st1[row*8 + w] = s1; st2[row*8 + w] = s2;
          }
        }
      __syncthreads();
      if (tid < 32){
        float s1 = 0.f, s2 = 0.f;
        #pragma unroll
        for (int k = 0; k < 8; k++){ s1 += st1[tid*8 + k]; s2 += st2[tid*8 + k]; }
        const float mu = s1 * (1.0f/256.0f);
        const float var = s2 * (1.0f/256.0f) - mu*mu;
        muA[tid] = mu; rsA[tid] = rsqrtf(var + 1e-5f);
      }
      __syncthreads();
      #pragma unroll
      for (int ct = 0; ct < 2; ct++){
        const int col = w*32 + ct*16 + fr;
        const float lw = lnS[lay*512 + col], lb = lnB[lay*512 + col];
        #pragma unroll
        for (int rt = 0; rt < 2; rt++)
          #pragma unroll
          for (int j = 0; j < 4; j++){
            const int row = rt*16 + hi4 + j;
            X[row*264 + col] = f2bf((val[rt][ct][j] - muA[row]) * rsA[row] * lw + lb);
          }
      }
      __syncthreads();
    }

    {
      f32x4 acc2[2][2] = {};
      for (int c = 0; c < 8; c++){
        u16* Yc = Yb + (c & 1) * 8448;
        bf16v8 w1r[8][2];
        #pragma unroll
        for (int ks = 0; ks < 8; ks++)
          #pragma unroll
          for (int ct = 0; ct < 2; ct++)
            w1r[ks][ct] = __builtin_bit_cast(bf16v8, *(const uint4*)(F1 + (long)((c*16 + w*2 + ct)*8 + ks)*512 + l*8));
        f32x4 acc1[2][2] = {};
        __builtin_amdgcn_s_setprio(1);
        #pragma unroll
        for (int ks = 0; ks < 8; ks++){
          bf16v8 a0 = __builtin_bit_cast(bf16v8, *(const uint4*)&X[fr*264 + ks*32 + ko]);
          bf16v8 a1 = __builtin_bit_cast(bf16v8, *(const uint4*)&X[(16+fr)*264 + ks*32 + ko]);
          #pragma unroll
          for (int ct = 0; ct < 2; ct++){
            acc1[0][ct] = __builtin_amdgcn_mfma_f32_16x16x32_bf16(a0, w1r[ks][ct], acc1[0][ct], 0, 0, 0);
            acc1[1][ct] = __builtin_amdgcn_mfma_f32_16x16x32_bf16(a1, w1r[ks][ct], acc1[1][ct], 0, 0, 0);
          }
        }
        __builtin_amdgcn_s_setprio(0);
        bf16v8 w2r[8][2];
        #pragma unroll
        for (int ks = 0; ks < 8; ks++)
          #pragma unroll
          for (int ct = 0; ct < 2; ct++)
            w2r[ks][ct] = __builtin_bit_cast(bf16v8, *(const uint4*)(F2 + (long)((w*2+ct)*64 + c*8 + ks)*512 + l*8));
        #pragma unroll
        for (int ct = 0; ct < 2; ct++){
          const float bb = f1B[lay*2048 + c*256 + w*32 + ct*16 + fr];
          #pragma unroll
          for (int rt = 0; rt < 2; rt++)
            #pragma unroll
            for (int j = 0; j < 4; j++)
              Yc[(rt*16 + hi4 + j)*264 + w*32 + ct*16 + fr] = f2bf(fmaxf(acc1[rt][ct][j] + bb, 0.0f));
        }
        __syncthreads();
        __builtin_amdgcn_s_setprio(1);
        #pragma unroll
        for (int ks = 0; ks < 8; ks++){
          bf16v8 a0 = __builtin_bit_cast(bf16v8, *(const uint4*)&Yc[fr*264 + ks*32 + ko]);
          bf16v8 a1 = __builtin_bit_cast(bf16v8, *(const uint4*)&Yc[(16+fr)*264 + ks*32 + ko]);
          #pragma unroll
          for (int ct = 0; ct < 2; ct++){
            acc2[0][ct] = __builtin_amdgcn_mfma_f32_16x16x32_bf16(a0, w2r[ks][ct], acc2[0][ct], 0, 0, 0);
            acc2[1][ct] = __builtin_amdgcn_mfma_f32_16x16x32_bf16(a1, w2r[ks][ct], acc2[1][ct], 0, 0, 0);
          }
        }
        __builtin_amdgcn_s_setprio(0);
      }
      __syncthreads();
      float val[2][2][4];
      #pragma unroll
      for (int ct = 0; ct < 2; ct++){
        const int col = w*32 + ct*16 + fr;
        const float bb = f2B[lay*256 + col];
        #pragma unroll
        for (int rt = 0; rt < 2; rt++)
          #pragma unroll
          for (int j = 0; j < 4; j++)
            val[rt][ct][j] = acc2[rt][ct][j] + bb + bf2f(X[(rt*16 + hi4 + j)*264 + col]);
      }
      #pragma unroll
      for (int rt = 0; rt < 2; rt++)
        #pragma unroll
        for (int j = 0; j < 4; j++){
          float s1 = val[rt][0][j] + val[rt][1][j];
          float s2 = val[rt][0][j]*val[rt][0][j] + val[rt][1][j]*val[rt][1][j];
          #pragma unroll
          for (int o = 1; o < 16; o <<= 1){ s1 += __shfl_xor(s1, o); s2 += __shfl_xor(s2, o); }
          if (fr == 0){
            const int row = rt*16 + hi4 + j;
            st1[row*8 + w] = s1; st2[row*8 + w] = s2;
          }
        }
      __syncthreads();
      if (tid < 32){
        float s1 = 0.f, s2 = 0.f;
        #pragma unroll
        for (int k = 0; k < 8; k++){ s1 += st1[tid*8 + k]; s2 += st2[tid*8 + k]; }
        const float mu = s1 * (1.0f/256.0f);
        const float var = s2 * (1.0f/256.0f) - mu*mu;
        muA[tid] = mu; rsA[tid] = rsqrtf(var + 1e-5f);
      }
      __syncthreads();
      #pragma unroll
      for (int ct = 0; ct < 2; ct++){
        const int col = w*32 + ct*16 + fr;
        const float lw = lnS[lay*512 + 256 + col], lb = lnB[lay*512 + 256 + col];
        #pragma unroll
        for (int rt = 0; rt < 2; rt++)
          #pragma unroll
          for (int j = 0; j < 4; j++){
            const int row = rt*16 + hi4 + j;
            X[row*264 + col] = f2bf((val[rt][ct][j] - muA[row]) * rsA[row] * lw + lb);
          }
      }
      __syncthreads();
    }
  }

  for (int idx = tid; idx < 736; idx += 512){
    const int row = idx >> 5, c8 = (idx & 31) * 8;
    *(uint4*)(se + (tb + row)*256 + c8) = *(const uint4*)&X[row*264 + c8];
  }
}

// ---------- glob MLP stage 1
__global__ __launch_bounds__(256) void glob1_k(const float* __restrict__ xg, const float* __restrict__ w1,
                                               const float* __restrict__ b1, u16* __restrict__ h){
  int b = blockIdx.x, d = threadIdx.x;
  float s = b1[d];
  #pragma unroll
  for (int k = 0; k < 16; k++) s += xg[b*16 + k] * w1[k*256 + d];
  h[(long)b*256 + d] = f2bf(gelu_fast(s));
}

// ---------- event sequence fill
__global__ __launch_bounds__(64) void fill_se(u16* __restrict__ se, const float* __restrict__ cls_task,
                                              const u16* __restrict__ globo, const float* __restrict__ pos_emb,
                                              const float* __restrict__ empty_emb){
  int bt = blockIdx.x;
  int b = bt / NTOKE, tk = bt % NTOKE;
  int t = threadIdx.x;
  u16* d = se + (long)bt * D_MOD;
  #pragma unroll
  for (int j = 0; j < 4; j++){
    int c = t*4 + j;
    float v;
    if (tk < 7) v = cls_task[tk*D_MOD + c];
    else if (tk == 7) v = bf2f(globo[(long)b*D_MOD + c]) + pos_emb[c];
    else v = empty_emb[c] + pos_emb[(tk - 7)*D_MOD + c];
    d[c] = f2bf(v);
  }
}

// ---------- scatter module CLS into event sequence (+pos_emb)
__global__ __launch_bounds__(64) void scatter_mod(u16* __restrict__ se, const u16* __restrict__ seqc,
                                                  const int* __restrict__ m2e, const int* __restrict__ mpos,
                                                  const int* __restrict__ starts,
                                                  const float* __restrict__ pos_emb){
  int m = blockIdx.x, t = threadIdx.x;
  int e = m2e[m], p = mpos[m];
  const u16* src = seqc + ((long)starts[m] + m) * D_MOD;
  u16* dst = se + ((long)e * NTOKE + 8 + p) * D_MOD;
  const float* pe = pos_emb + (long)(1 + p) * D_MOD;
  #pragma unroll
  for (int j = 0; j < 4; j++){
    int c = t*4 + j;
    dst[c] = f2bf(bf2f(src[c]) + pe[c]);
  }
}

// ---------- heads
__global__ __launch_bounds__(64) void heads_k(const u16* __restrict__ se, const float* __restrict__ hw,
                                              const float* __restrict__ hb, float* __restrict__ out){
  int b = blockIdx.x, t = threadIdx.x;
  __shared__ float raw[16];
  if (t < 16){
    int tok = (t < 4) ? 0 : (t <= 8) ? (t - 3) : (t <= 11) ? 5 : 6;
    const u16* e = se + ((long)b * NTOKE + tok) * D_MOD;
    float s = hb[t];
    for (int d = 0; d < 256; d++) s += bf2f(e[d]) * hw[d*16 + t];
    raw[t] = s;
  }
  __syncthreads();
  if (t < 16){
    float v = raw[t];
    float r;
    if (t <= 8 || t == 12){
      r = fmaxf(v, 0.0f) + log1pf(__expf(-fabsf(v)));
    } else if (t <= 11){
      float n = sqrtf(raw[9]*raw[9] + raw[10]*raw[10] + raw[11]*raw[11]);
      r = v / fmaxf(n, 1e-12f);
    } else {
      float n = sqrtf(raw[13]*raw[13] + raw[14]*raw[14] + raw[15]*raw[15]);
      r = v / fmaxf(n, 1e-12f);
    }
    out[b*16 + t] = r;
  }
}

extern "C" void kernel_launch(void* const* d_in, const int* in_sizes, int n_in,
                              void* d_out, int out_size, void* d_ws, size_t ws_size,
                              hipStream_t stream){
  const float* feats      = (const float*)d_in[0];
  const float* coords     = (const float*)d_in[1];
  const int*   batch_ids  = (const int*)d_in[2];
  const int*   m2e        = (const int*)d_in[3];
  const int*   mpos       = (const int*)d_in[4];
  const float* x_glob     = (const float*)d_in[5];
  const float* cls_mod    = (const float*)d_in[6];
  const float* empty_emb  = (const float*)d_in[7];
  const float* cls_task   = (const float*)d_in[8];
  const float* pos_emb    = (const float*)d_in[9];
  const float* mod_attn_w = (const float*)d_in[10];
  const float* mod_attn_b = (const float*)d_in[11];
  const float* mod_rel    = (const float*)d_in[12];
  const float* mod_ln_s   = (const float*)d_in[13];
  const float* mod_ln_b   = (const float*)d_in[14];
  const float* mod_ffn_w1 = (const float*)d_in[15];
  const float* mod_ffn_b1 = (const float*)d_in[16];
  const float* mod_ffn_w2 = (const float*)d_in[17];
  const float* mod_ffn_b2 = (const float*)d_in[18];
  const float* glob_w1    = (const float*)d_in[19];
  const float* glob_b1    = (const float*)d_in[20];
  const float* glob_w2    = (const float*)d_in[21];
  const float* glob_b2    = (const float*)d_in[22];
  const float* evt_attn_w = (const float*)d_in[23];
  const float* evt_attn_b = (const float*)d_in[24];
  const float* evt_ln_s   = (const float*)d_in[25];
  const float* evt_ln_b   = (const float*)d_in[26];
  const float* evt_ffn_w1 = (const float*)d_in[27];
  const float* evt_ffn_b1 = (const float*)d_in[28];
  const float* evt_ffn_w2 = (const float*)d_in[29];
  const float* evt_ffn_b2 = (const float*)d_in[30];
  const float* head_w     = (const float*)d_in[31];
  const float* head_b     = (const float*)d_in[32];
  float* out = (float*)d_out;

  const int N = in_sizes[0] / 256;
  const int M = in_sizes[3];
  const int B = in_sizes[5] / 16;
  const long CROWS   = (long)M + N;                         // 54306
  const long CROWS_P = (((CROWS + 255) >> 8) << 8) + 256;   // pad to x256 + overrun guard
  const long TE  = (long)B * NTOKE;

  char* ws = (char*)d_ws;
  u16* modWT   = (u16*)ws;
  u16* evtWT   = modWT + 8L*65536;
  u16* modF1T  = evtWT + 12L*65536;
  u16* modF2T  = modF1T + 2L*262144;
  u16* evtF1T  = modF2T + 2L*262144;
  u16* evtF2T  = evtF1T + 3L*524288;
  u16* globW2T = evtF2T + 3L*524288;
  size_t off = 11468800;
  int* counts = (int*)(ws + off); off += 16*1024;
  int* starts = (int*)(ws + off); off += 16*1024;
  float* scc  = (float*)(ws + off); off += ((size_t)CROWS_P*12 + 255) & ~(size_t)255;
  u16* seqc   = (u16*)(ws + off); off += (size_t)CROWS_P * D_MOD * 2;
  off = (off + 255) & ~(size_t)255;
  const size_t OFF_BIG = off;
  u16* qkv   = (u16*)(ws + OFF_BIG);
  u16* attno = (u16*)(ws + OFF_BIG + (size_t)CROWS_P*768*2);
  u16* ffh   = (u16*)(ws + OFF_BIG);
  u16* se    = (u16*)(ws + OFF_BIG);
  u16* globh = (u16*)(ws + OFF_BIG + 12*1024*1024);
  u16* globo = (u16*)(ws + OFF_BIG + 13*1024*1024);
  u16* evtWP  = (u16*)(ws + OFF_BIG + 120L*1024*1024);
  u16* evtF1P = evtWP + 12L*65536;
  u16* evtF2P = evtF1P + 3L*524288;

  prep_all<<<5440, 256, 0, stream>>>(mod_attn_w, evt_attn_w, mod_ffn_w1, mod_ffn_w2,
                                     evt_ffn_w1, evt_ffn_w2, glob_w2,
                                     modWT, evtWT, modF1T, modF2T, evtF1T, evtF2T, globW2T,
                                     evtWP, evtF1P, evtF2P);

  hipMemsetAsync(counts, 0, (size_t)M*4, stream);
  hipMemsetAsync(scc, 0, (size_t)CROWS_P*12, stream);
  hipMemsetAsync(seqc + CROWS*D_MOD, 0, (size_t)(CROWS_P - CROWS)*D_MOD*2, stream);
  hipMemsetAsync(attno + CROWS*D_MOD, 0, (size_t)(CROWS_P - CROWS)*D_MOD*2, stream);
  count_k<<<(N + 255)/256, 256, 0, stream>>>(batch_ids, counts, N);
  scan_k<<<1, 1024, 0, stream>>>(counts, starts, M);
  cls_fill<<<M, 64, 0, stream>>>(seqc, cls_mod, starts);
  scatter_k<<<N, 64, 0, stream>>>(feats, coords, batch_ids, seqc, scc);

  const int RB = (int)(CROWS_P / 256);
  const int RB2 = (int)(CROWS_P / 128);
  for (int l = 0; l < 2; l++){
    gemm256<0><<<dim3(6, RB), 512, 0, stream>>>(seqc, modWT + (long)l*4*65536,
        mod_attn_b + l*1024, nullptr, qkv, 256, 768);
    mod_attn_all<<<dim3(M, NHEAD), 256, 0, stream>>>(qkv, scc, mod_rel + l*24, counts, starts, attno);
    gemm_ln<<<dim3(1, RB2), 512, 0, stream>>>(attno, modWT + ((long)l*4+3)*65536,
        mod_attn_b + l*1024 + 768, seqc, seqc, 256,
        mod_ln_s + (l*2)*256, mod_ln_b + (l*2)*256);
    gemm256<1><<<dim3(8, RB), 512, 0, stream>>>(seqc, modF1T + (long)l*262144,
        mod_ffn_b1 + l*1024, nullptr, ffh, 256, 1024);
    gemm_ln<<<dim3(1, RB2), 512, 0, stream>>>(ffh, modF2T + (long)l*262144,
        mod_ffn_b2 + l*256, seqc, seqc, 1024,
        mod_ln_s + (l*2+1)*256, mod_ln_b + (l*2+1)*256);
  }

  hipMemsetAsync(globh, 0, 256*256*2, stream);
  glob1_k<<<B, 256, 0, stream>>>(x_glob, glob_w1, glob_b1, globh);
  gemm256<0><<<dim3(2, 1), 512, 0, stream>>>(globh, globW2T, glob_b2, nullptr, globo, 256, 256);
  fill_se<<<(int)TE, 64, 0, stream>>>(se, cls_task, globo, pos_emb, empty_emb);
  scatter_mod<<<M, 64, 0, stream>>>(se, seqc, m2e, mpos, starts, pos_emb);

  evt_fused<<<B, 512, 0, stream>>>(se, evtWP, evt_attn_b, evtF1P, evt_ffn_b1,
                                   evtF2P, evt_ffn_b2, evt_ln_s, evt_ln_b);

  heads_k<<<B, 64, 0, stream>>>(se, head_w, head_b, out);
}

// Round 24
// 825.843 us; speedup vs baseline: 1.0324x; 1.0324x over previous
//
#include <hip/hip_runtime.h>
#include <hip/hip_bf16.h>
#include <math.h>

typedef unsigned short u16;
typedef unsigned int u32;
typedef __bf16 bf16v8 __attribute__((ext_vector_type(8)));
typedef _Float16 f16v8 __attribute__((ext_vector_type(8)));
typedef __attribute__((ext_vector_type(4))) float f32x4;

#define D_MOD 256
#define NHEAD 8
#define DHEAD 32
#define SEQL 97
#define NTOKE 23

__device__ __forceinline__ float bf2f(u16 u){
  union { unsigned int i; float f; } x; x.i = ((unsigned int)u) << 16; return x.f;
}
__device__ __forceinline__ u16 f2bf(float f){
  return __builtin_bit_cast(u16, (__bf16)f);
}
__device__ __forceinline__ float gelu_fast(float v){
  float z = v * 0.70710678118654752f;
  float az = fabsf(z);
  float t = __builtin_amdgcn_rcpf(fmaf(0.3275911f, az, 1.0f));
  float p = t*(0.254829592f + t*(-0.284496736f + t*(1.421413741f + t*(-1.453152027f + t*1.061405429f))));
  float e = __expf(-z*z);
  float y = 1.0f - p*e;
  float erfz = copysignf(y, z);
  return 0.5f * v * (1.0f + erfz);
}
__device__ __forceinline__ void gld16(const void* g, void* l){
  __builtin_amdgcn_global_load_lds((const __attribute__((address_space(1))) void*)g,
                                   (__attribute__((address_space(3))) void*)l, 16, 0, 0);
}

// ---------- ONE-SHOT weight prep (r19-exact): transpose + event fragment-packing
__global__ __launch_bounds__(256) void prep_all(
    const float* __restrict__ aw, const float* __restrict__ ew,
    const float* __restrict__ f1m, const float* __restrict__ f2m,
    const float* __restrict__ f1e, const float* __restrict__ f2e,
    const float* __restrict__ gw2,
    u16* __restrict__ modWT, u16* __restrict__ evtWT,
    u16* __restrict__ modF1T, u16* __restrict__ modF2T,
    u16* __restrict__ evtF1T, u16* __restrict__ evtF2T,
    u16* __restrict__ globW2T,
    u16* __restrict__ WP, u16* __restrict__ F1P, u16* __restrict__ F2P)
{
  const int id = blockIdx.x;
  const float* src; u16* dst; u16* pk = nullptr; int K, N, kx, nx, t; long sS, dS;
  if (id < 512)      { t = id;        src = aw;  dst = modWT;   K=256;  N=256;  kx=8;  nx=8;  sS=65536;  dS=65536;  }
  else if (id < 1280){ t = id - 512;  src = ew;  dst = evtWT;   K=256;  N=256;  kx=8;  nx=8;  sS=65536;  dS=65536;  pk = WP;  }
  else if (id < 1792){ t = id - 1280; src = f1m; dst = modF1T;  K=256;  N=1024; kx=8;  nx=32; sS=262144; dS=262144; }
  else if (id < 2304){ t = id - 1792; src = f2m; dst = modF2T;  K=1024; N=256;  kx=32; nx=8;  sS=262144; dS=262144; }
  else if (id < 3840){ t = id - 2304; src = f1e; dst = evtF1T;  K=256;  N=2048; kx=8;  nx=64; sS=524288; dS=524288; pk = F1P; }
  else if (id < 5376){ t = id - 3840; src = f2e; dst = evtF2T;  K=2048; N=256;  kx=64; nx=8;  sS=524288; dS=524288; pk = F2P; }
  else               { t = id - 5376; src = gw2; dst = globW2T; K=256;  N=256;  kx=8;  nx=8;  sS=65536;  dS=65536;  }
  const int per = kx * nx;
  const int z = t / per, rem = t % per;
  const int k0 = (rem % kx) * 32, n0 = (rem / kx) * 32;
  src += (long)z * sS; dst += (long)z * dS;
  __shared__ float tt[32][33];
  const int tx = threadIdx.x & 31, ty = threadIdx.x >> 5;
  #pragma unroll
  for (int r = ty; r < 32; r += 8)
    tt[r][tx] = src[(long)(k0 + r) * N + n0 + tx];
  __syncthreads();
  #pragma unroll
  for (int r = ty; r < 32; r += 8)
    dst[(long)(n0 + r) * K + k0 + tx] = f2bf(tt[tx][r]);
  if (pk && threadIdx.x < 128){
    const int q = threadIdx.x >> 6, l = threadIdx.x & 63;
    const int nb = (n0 >> 4) + q, kb = k0 >> 5;
    const int c = q*16 + (l & 15);
    const int klb = (l >> 4) * 8;
    const long fragi = (long)nb * (K/32) + kb;
    u16 frag[8];
    #pragma unroll
    for (int e = 0; e < 8; e++) frag[e] = f2bf(tt[klb + e][c]);
    u16* d = pk + (long)z * (long)N * K + (fragi*64 + l)*8;
    *(uint4*)d = *(const uint4*)frag;
  }
}

// ---------- counts / scan / scatter
__global__ void count_k(const int* __restrict__ bids, int* __restrict__ counts, int n){
  int i = blockIdx.x * blockDim.x + threadIdx.x;
  if (i < n) atomicAdd(&counts[bids[i]], 1);
}

__global__ void scan_k(const int* __restrict__ counts, int* __restrict__ starts, int M){
  __shared__ int buf[1024];
  int t = threadIdx.x;
  int v = (t < M) ? counts[t] : 0;
  buf[t] = v;
  __syncthreads();
  for (int o = 1; o < 1024; o <<= 1){
    int x = (t >= o) ? buf[t - o] : 0;
    __syncthreads();
    buf[t] += x;
    __syncthreads();
  }
  if (t < M) starts[t] = buf[t] - v;
}

__global__ __launch_bounds__(64) void cls_fill(u16* __restrict__ seqc, const float* __restrict__ cls_mod,
                                               const int* __restrict__ starts){
  int m = blockIdx.x, t = threadIdx.x;
  long row = (long)starts[m] + m;
  const float4 v = *(const float4*)(cls_mod + t * 4);
  u16* d = seqc + row * D_MOD + t * 4;
  d[0] = f2bf(v.x); d[1] = f2bf(v.y); d[2] = f2bf(v.z); d[3] = f2bf(v.w);
}

__global__ __launch_bounds__(64) void scatter_k(const float* __restrict__ feats, const float* __restrict__ coords,
                          const int* __restrict__ bids, u16* __restrict__ seqc, float* __restrict__ scc){
  int i = blockIdx.x, t = threadIdx.x;
  long row = (long)i + bids[i] + 1;
  const float4 v = *(const float4*)(feats + (long)i * D_MOD + t * 4);
  u16* d = seqc + row * D_MOD + t * 4;
  d[0] = f2bf(v.x); d[1] = f2bf(v.y); d[2] = f2bf(v.z); d[3] = f2bf(v.w);
  if (t < 3) scc[row * 3 + t] = coords[(long)i * 3 + t];
}

// ---------- 256x128 bf16 MFMA GEMM, BK=64, 8 waves (r20-exact; 48KB LDS -> 3 blocks/CU)
template<int EPI> // 0 none, 1 gelu, 2 relu, 3 +resid
__global__ __launch_bounds__(512) void gemm256(
    const u16* __restrict__ A, const u16* __restrict__ Wt,
    const float* __restrict__ bias, const u16* __restrict__ resid,
    u16* __restrict__ C, int K, int N)
{
  __shared__ char smemraw[49152];          // As [2][256][32]=32KB + Bs [2][128][32]=16KB
  u16* As = (u16*)smemraw;
  u16* Bs = (u16*)(smemraw + 32768);
  float* stg = (float*)smemraw;            // epilogue [32][132] f32 (16.9KB, aliases As)

  const int tid = threadIdx.x;
  const int w = tid >> 6, l = tid & 63;
  const int wr = w >> 1, wc = w & 1;

  const long nwg = (long)gridDim.x * gridDim.y;
  const long orig = (long)blockIdx.y * gridDim.x + blockIdx.x;
  const long q = nwg >> 3, r = nwg & 7;
  const long xcd = orig & 7, idx = orig >> 3;
  const long swz = (xcd < r ? xcd * (q + 1) : r * (q + 1) + (xcd - r) * q) + idx;
  const int colb = (int)(swz % gridDim.x);
  const long rowb = swz / gridDim.x;
  const long row0 = rowb * 256;
  const int col0 = colb * 128;

  const int fr = l & 15;
  const int ko = (l >> 4) * 8;
  f32x4 acc[4][4] = {};

  for (int kt = 0; kt < K; kt += 64){
    __syncthreads();
    #pragma unroll
    for (int p = 0; p < 4; p++){           // A: 2048 slots of 16B
      const int s = p * 512 + tid;
      const int inner = s & 1023, half = s >> 10;
      gld16(A + (row0 + (inner >> 2)) * K + kt + half*32 + (inner & 3)*8,
            As + (p*512 + w*64) * 8);
    }
    #pragma unroll
    for (int p = 0; p < 2; p++){           // B: 1024 slots of 16B
      const int s = p * 512 + tid;
      const int inner = s & 511, half = s >> 9;
      gld16(Wt + (long)(col0 + (inner >> 2)) * K + kt + half*32 + (inner & 3)*8,
            Bs + (p*512 + w*64) * 8);
    }
    __syncthreads();
    #pragma unroll
    for (int kk2 = 0; kk2 < 2; kk2++){
      bf16v8 af[4], bfv[4];
      #pragma unroll
      for (int mi = 0; mi < 4; mi++)
        af[mi] = __builtin_bit_cast(bf16v8, *(const uint4*)(As + kk2*8192 + (wr*64 + mi*16 + fr)*32 + ko));
      #pragma unroll
      for (int ni = 0; ni < 4; ni++)
        bfv[ni] = __builtin_bit_cast(bf16v8, *(const uint4*)(Bs + kk2*4096 + (wc*64 + ni*16 + fr)*32 + ko));
      #pragma unroll
      for (int mi = 0; mi < 4; mi++)
        #pragma unroll
        for (int ni = 0; ni < 4; ni++)
          acc[mi][ni] = __builtin_amdgcn_mfma_f32_16x16x32_bf16(af[mi], bfv[ni], acc[mi][ni], 0, 0, 0);
    }
  }

  // ---- epilogue: 8 passes of 32 rows; staged f32 -> coalesced dwordx4 stores
  const int rq = (l >> 4) * 4;
  #pragma unroll
  for (int p = 0; p < 8; p++){
    __syncthreads();
    if (wr == (p >> 1)){
      #pragma unroll
      for (int mm = 0; mm < 2; mm++){
        const int mi = (p & 1) * 2 + mm;
        #pragma unroll
        for (int ni = 0; ni < 4; ni++){
          const int coll = wc*64 + ni*16 + fr;
          const float bb = bias[col0 + coll];
          #pragma unroll
          for (int j = 0; j < 4; j++){
            float v = acc[mi][ni][j] + bb;
            if (EPI == 1) v = gelu_fast(v);
            if (EPI == 2) v = fmaxf(v, 0.0f);
            stg[(mm*16 + rq + j) * 132 + coll] = v;
          }
        }
      }
    }
    __syncthreads();
    {
      const int rowl = tid >> 4;           // 512 slots: 32 rows x 16 col8
      const int cs = (tid & 15) * 8;
      const long gbase = (row0 + p*32 + rowl) * (long)N + col0 + cs;
      float4 lo = *(const float4*)(stg + rowl*132 + cs);
      float4 hi = *(const float4*)(stg + rowl*132 + cs + 4);
      float vv[8] = {lo.x, lo.y, lo.z, lo.w, hi.x, hi.y, hi.z, hi.w};
      if (EPI == 3){
        uint4 rv = *(const uint4*)(resid + gbase);
        const u16* rp = (const u16*)&rv;
        #pragma unroll
        for (int e = 0; e < 8; e++) vv[e] += bf2f(rp[e]);
      }
      uint4 ov;
      u16* op = (u16*)&ov;
      #pragma unroll
      for (int e = 0; e < 8; e++) op[e] = f2bf(vv[e]);
      *(uint4*)(C + gbase) = ov;
    }
  }
}

// ---------- 128x256 bf16 MFMA GEMM + residual + LayerNorm fused epilogue (K=256 only:
// B-traffic doubling is cheap at small K; removes a standalone ln_k pass).
__global__ __launch_bounds__(512) void gemm_ln(
    const u16* __restrict__ A, const u16* __restrict__ Wt,
    const float* __restrict__ bias, const u16* __restrict__ resid,
    u16* __restrict__ C, int K,
    const float* __restrict__ lnS, const float* __restrict__ lnB)
{
  __shared__ char smemraw[49152];          // As [2][128][32]=16KB + Bs [2][256][32]=32KB
  u16* As = (u16*)smemraw;
  u16* Bs = (u16*)(smemraw + 16384);
  float* stg = (float*)smemraw;            // epilogue [32][260] f32 (33.3KB, aliases)

  const int tid = threadIdx.x;
  const int w = tid >> 6, l = tid & 63;
  const int wr = w >> 2, wc = w & 3;       // wr 0..1 (64-row group), wc 0..3 (64-col group)

  const long nwg = gridDim.y;              // gridDim.x == 1
  const long orig = blockIdx.y;
  const long q = nwg >> 3, r = nwg & 7;
  const long xcd = orig & 7, idx = orig >> 3;
  const long swz = (xcd < r ? xcd * (q + 1) : r * (q + 1) + (xcd - r) * q) + idx;
  const long row0 = swz * 128;

  const int fr = l & 15;
  const int ko = (l >> 4) * 8;
  f32x4 acc[4][4] = {};

  for (int kt = 0; kt < K; kt += 64){
    __syncthreads();
    #pragma unroll
    for (int p = 0; p < 2; p++){           // A: 1024 slots of 16B
      const int s = p * 512 + tid;
      const int inner = s & 511, half = s >> 9;
      gld16(A + (row0 + (inner >> 2)) * K + kt + half*32 + (inner & 3)*8,
            As + (p*512 + w*64) * 8);
    }
    #pragma unroll
    for (int p = 0; p < 4; p++){           // B: 2048 slots of 16B (all 256 N-rows)
      const int s = p * 512 + tid;
      const int inner = s & 1023, half = s >> 10;
      gld16(Wt + (long)(inner >> 2) * K + kt + half*32 + (inner & 3)*8,
            Bs + (p*512 + w*64) * 8);
    }
    __syncthreads();
    #pragma unroll
    for (int kk2 = 0; kk2 < 2; kk2++){
      bf16v8 af[4], bfv[4];
      #pragma unroll
      for (int mi = 0; mi < 4; mi++)
        af[mi] = __builtin_bit_cast(bf16v8, *(const uint4*)(As + kk2*4096 + (wr*64 + mi*16 + fr)*32 + ko));
      #pragma unroll
      for (int ni = 0; ni < 4; ni++)
        bfv[ni] = __builtin_bit_cast(bf16v8, *(const uint4*)(Bs + kk2*8192 + (wc*64 + ni*16 + fr)*32 + ko));
      #pragma unroll
      for (int mi = 0; mi < 4; mi++)
        #pragma unroll
        for (int ni = 0; ni < 4; ni++)
          acc[mi][ni] = __builtin_amdgcn_mfma_f32_16x16x32_bf16(af[mi], bfv[ni], acc[mi][ni], 0, 0, 0);
    }
  }

  // ---- epilogue: 4 passes of 32 rows; full 256-col row staged -> +resid -> LN -> bf16
  const int rq = (l >> 4) * 4;
  #pragma unroll
  for (int p = 0; p < 4; p++){
    __syncthreads();
    if (wr == (p >> 1)){
      #pragma unroll
      for (int mm = 0; mm < 2; mm++){
        const int mi = (p & 1) * 2 + mm;
        #pragma unroll
        for (int ni = 0; ni < 4; ni++){
          const int coll = wc*64 + ni*16 + fr;
          const float bb = bias[coll];
          #pragma unroll
          for (int j = 0; j < 4; j++)
            stg[(mm*16 + rq + j) * 260 + coll] = acc[mi][ni][j] + bb;
        }
      }
    }
    __syncthreads();
    {
      const int rowl = tid >> 4;           // 32 rows x 16 threads/row
      const int c0 = (tid & 15) * 16;
      const long gbase = (row0 + p*32 + rowl) * 256 + c0;
      float v[16];
      uint4 r0 = *(const uint4*)(resid + gbase);
      uint4 r1 = *(const uint4*)(resid + gbase + 8);
      const u16* rp0 = (const u16*)&r0;
      const u16* rp1 = (const u16*)&r1;
      #pragma unroll
      for (int e = 0; e < 8; e++){
        v[e]     = stg[rowl*260 + c0 + e]     + bf2f(rp0[e]);
        v[8 + e] = stg[rowl*260 + c0 + 8 + e] + bf2f(rp1[e]);
      }
      float sum = 0.f, sq = 0.f;
      #pragma unroll
      for (int e = 0; e < 16; e++){ sum += v[e]; sq += v[e]*v[e]; }
      #pragma unroll
      for (int o = 1; o < 16; o <<= 1){
        sum += __shfl_xor(sum, o);
        sq  += __shfl_xor(sq,  o);
      }
      const float mu = sum * (1.0f/256.0f);
      const float var = sq * (1.0f/256.0f) - mu*mu;
      const float rs = rsqrtf(var + 1e-5f);
      uint4 o0, o1;
      u16* op0 = (u16*)&o0; u16* op1 = (u16*)&o1;
      #pragma unroll
      for (int e = 0; e < 8; e++){
        op0[e] = f2bf((v[e]     - mu) * rs * lnS[c0 + e]     + lnB[c0 + e]);
        op1[e] = f2bf((v[8 + e] - mu) * rs * lnS[c0 + 8 + e] + lnB[c0 + 8 + e]);
      }
      *(uint4*)(C + gbase)     = o0;
      *(uint4*)(C + gbase + 8) = o1;
    }
  }
}

// ---------- LayerNorm in-place, 4 rows per block
__global__ __launch_bounds__(256) void ln_k(u16* __restrict__ x, const float* __restrict__ s,
                                            const float* __restrict__ b, long nrows){
  const long row = (long)blockIdx.x * 4 + (threadIdx.x >> 6);
  if (row >= nrows) return;
  const int t = threadIdx.x & 63;
  u16* xr = x + row * D_MOD;
  uint2 rv = *(const uint2*)(xr + t * 4);
  float v0 = bf2f((u16)(rv.x & 0xffffu));
  float v1 = bf2f((u16)(rv.x >> 16));
  float v2 = bf2f((u16)(rv.y & 0xffffu));
  float v3 = bf2f((u16)(rv.y >> 16));
  float sum = v0 + v1 + v2 + v3;
  float sq  = v0*v0 + v1*v1 + v2*v2 + v3*v3;
  #pragma unroll
  for (int o = 32; o > 0; o >>= 1){
    sum += __shfl_xor(sum, o, 64);
    sq  += __shfl_xor(sq,  o, 64);
  }
  float mu = sum * (1.0f/256.0f);
  float var = sq * (1.0f/256.0f) - mu*mu;
  float rs = rsqrtf(var + 1e-5f);
  int c = t * 4;
  u16 o0 = f2bf((v0-mu)*rs*s[c+0]+b[c+0]);
  u16 o1 = f2bf((v1-mu)*rs*s[c+1]+b[c+1]);
  u16 o2 = f2bf((v2-mu)*rs*s[c+2]+b[c+2]);
  u16 o3 = f2bf((v3-mu)*rs*s[c+3]+b[c+3]);
  uint2 wv;
  wv.x = (unsigned)o0 | ((unsigned)o1 << 16);
  wv.y = (unsigned)o2 | ((unsigned)o3 << 16);
  *(uint2*)(xr + t * 4) = wv;
}

// ---------- module attention body (r9-exact math), NT = #16-key-tiles, static bounds
template<int NT>
__device__ __forceinline__ void attn_body(
    char* __restrict__ smemRaw,
    const u16* __restrict__ qkv, const float* __restrict__ scc,
    const float* __restrict__ rel, const int S, const long base,
    u16* __restrict__ out)
{
  constexpr int KS  = (NT + 1) / 2;
  constexpr int NK  = NT * 16;
  constexpr int STR = (KS * 32 <= 64) ? 64 : 128;
  constexpr int PBYTES = (NK * STR * 2 > NK * 132) ? NK * STR * 2 : NK * 132;
  u16* Pb = (u16*)smemRaw;
  u16* Vt = (u16*)(smemRaw + PBYTES);
  float* pj = (float*)(smemRaw + PBYTES + 32 * STR * 2);

  const int h = blockIdx.y;
  const int tid = threadIdx.x, w = tid >> 6, l = tid & 63;
  const int fr = l & 15, ko = (l >> 4) * 8;

  if (tid < NK){
    float v = 1e30f;
    if (tid < S){
      const float* s3 = scc + (base + tid) * 3;
      v = s3[0]*rel[h*3] + s3[1]*rel[h*3+1] + s3[2]*rel[h*3+2];
    }
    pj[tid] = v;
  }
  for (int idx = tid; idx < NK*32; idx += 256){
    int key = idx >> 5, d = idx & 31;
    float v = bf2f(qkv[(base + key)*768 + 512 + h*32 + d]);
    v = fminf(fmaxf(v, -60000.0f), 60000.0f);
    _Float16 hv = (_Float16)v;
    Vt[d*STR + (key ^ ((d & 7) << 3))] = __builtin_bit_cast(u16, hv);
  }
  for (int idx = tid; idx < 32*16; idx += 256){
    int d = idx >> 4, c = NK + (idx & 15);
    Vt[d*STR + (c ^ ((d & 7) << 3))] = 0;
  }
  for (int idx = tid; idx < NK*16; idx += 256){
    int row = idx >> 4, c = NK + (idx & 15);
    Pb[row*STR + (c ^ ((row & 7) << 3))] = 0;
  }
  __syncthreads();

  f32x4 accs[2][NT];
  bf16v8 kf[NT];
  #pragma unroll
  for (int nt = 0; nt < NT; nt++)
    kf[nt] = __builtin_bit_cast(bf16v8, *(const uint4*)(qkv + (base + nt*16 + fr)*768 + 256 + h*32 + ko));
  #pragma unroll
  for (int rr2 = 0; rr2 < 2; rr2++){
    const int rt = w + rr2*4;
    if (rt > NT - 1) break;
    bf16v8 qf = __builtin_bit_cast(bf16v8, *(const uint4*)(qkv + (base + rt*16 + fr)*768 + h*32 + ko));
    #pragma unroll
    for (int nt = 0; nt < NT; nt++){
      f32x4 z = {0.f, 0.f, 0.f, 0.f};
      accs[rr2][nt] = __builtin_amdgcn_mfma_f32_16x16x32_bf16(qf, kf[nt], z, 0, 0, 0);
    }
  }

  float pjr[NT];
  #pragma unroll
  for (int nt = 0; nt < NT; nt++) pjr[nt] = pj[nt*16 + fr];
  const float SCALE = 0.17677669529663687f;
  #pragma unroll
  for (int rr2 = 0; rr2 < 2; rr2++){
    const int rt = w + rr2*4;
    if (rt > NT - 1) break;
    #pragma unroll
    for (int j = 0; j < 4; j++){
      float x[NT], mx = -1e30f;
      #pragma unroll
      for (int nt = 0; nt < NT; nt++){
        x[nt] = accs[rr2][nt][j] * SCALE - pjr[nt];
        mx = fmaxf(mx, x[nt]);
      }
      #pragma unroll
      for (int o = 1; o < 16; o <<= 1) mx = fmaxf(mx, __shfl_xor(mx, o));
      float sum = 0.f;
      #pragma unroll
      for (int nt = 0; nt < NT; nt++){
        x[nt] = __expf(x[nt] - mx);
        sum += x[nt];
      }
      #pragma unroll
      for (int o = 1; o < 16; o <<= 1) sum += __shfl_xor(sum, o);
      const float inv = 1.0f / sum;
      const int row = rt*16 + (l >> 4)*4 + j;
      #pragma unroll
      for (int nt = 0; nt < NT; nt++){
        _Float16 hp = (_Float16)(x[nt] * inv);
        Pb[row*STR + ((nt*16 + fr) ^ ((row & 7) << 3))] = __builtin_bit_cast(u16, hp);
      }
    }
  }
  __syncthreads();

  f32x4 accO[2][2];
  #pragma unroll
  for (int rr2 = 0; rr2 < 2; rr2++){
    const int rt = w + rr2*4;
    if (rt > NT - 1) break;
    #pragma unroll
    for (int nt = 0; nt < 2; nt++){
      f32x4 z = {0.f, 0.f, 0.f, 0.f};
      accO[rr2][nt] = z;
    }
    #pragma unroll
    for (int ks = 0; ks < KS; ks++){
      const int prow = rt*16 + fr;
      f16v8 pa = __builtin_bit_cast(f16v8, *(const uint4*)(Pb + prow*STR + ((ks*32 + ko) ^ ((prow & 7) << 3))));
      #pragma unroll
      for (int nt = 0; nt < 2; nt++){
        const int vrow = nt*16 + fr;
        f16v8 vb = __builtin_bit_cast(f16v8, *(const uint4*)(Vt + vrow*STR + ((ks*32 + ko) ^ ((vrow & 7) << 3))));
        accO[rr2][nt] = __builtin_amdgcn_mfma_f32_16x16x32_f16(pa, vb, accO[rr2][nt], 0, 0, 0);
      }
    }
  }
  __syncthreads();

  float* O = (float*)smemRaw;
  #pragma unroll
  for (int rr2 = 0; rr2 < 2; rr2++){
    const int rt = w + rr2*4;
    if (rt > NT - 1) break;
    #pragma unroll
    for (int nt = 0; nt < 2; nt++)
      #pragma unroll
      for (int j = 0; j < 4; j++)
        O[(rt*16 + (l>>4)*4 + j)*33 + nt*16 + fr] = accO[rr2][nt][j];
  }
  __syncthreads();
  for (int idx = tid; idx < NK*16; idx += 256){
    const int row = idx >> 4;
    if (row >= S) continue;
    const int c = (idx & 15) * 2;
    const float f0 = O[row*33 + c], f1 = O[row*33 + c + 1];
    u32 pk = (u32)f2bf(f0) | ((u32)f2bf(f1) << 16);
    *(u32*)(out + (base + row)*256 + h*32 + c) = pk;
  }
}

// ---------- single-launch bucketed attention
__global__ __launch_bounds__(256) void mod_attn_all(
    const u16* __restrict__ qkv, const float* __restrict__ scc,
    const float* __restrict__ rel, const int* __restrict__ counts,
    const int* __restrict__ starts, u16* __restrict__ out)
{
  __shared__ __align__(16) char smem[37376];
  const int m = blockIdx.x;
  const int S = counts[m] + 1;
  const long base = (long)starts[m] + m;
  if (S <= 48)      attn_body<3>(smem, qkv, scc, rel, S, base, out);
  else if (S <= 80) attn_body<5>(smem, qkv, scc, rel, S, base, out);
  else              attn_body<7>(smem, qkv, scc, rel, S, base, out);
}

// ---------- FUSED 3-layer event transformer (r19-exact: packed weights + setprio)
__global__ __launch_bounds__(512, 1) void evt_fused(
    u16* __restrict__ se,
    const u16* __restrict__ attnWP, const float* __restrict__ attnB,
    const u16* __restrict__ f1P, const float* __restrict__ f1B,
    const u16* __restrict__ f2P, const float* __restrict__ f2B,
    const float* __restrict__ lnS, const float* __restrict__ lnB)
{
  __shared__ u16 X[32*264];
  __shared__ u16 Yb[2*32*264];
  __shared__ u16 Sb[8*32*40];
  __shared__ float st1[32*8], st2[32*8];
  __shared__ float muA[32], rsA[32];

  const int b = blockIdx.x;
  const int tid = threadIdx.x, w = tid >> 6, l = tid & 63;
  const int fr = l & 15, hi4 = (l >> 4) * 4, ko = (l >> 4) * 8;
  const long tb = (long)b * NTOKE;
  u16* Sw = Sb + w * 1280;
  u16* Y = Yb;

  for (int idx = tid; idx < 736; idx += 512){
    const int row = idx >> 5, c8 = (idx & 31) * 8;
    *(uint4*)&X[row*264 + c8] = *(const uint4*)(se + (tb + row)*256 + c8);
  }
  for (int idx = tid; idx < 288; idx += 512){
    const int row = 23 + (idx >> 5), c8 = (idx & 31) * 8;
    uint4 z = {0,0,0,0};
    *(uint4*)&X[row*264 + c8] = z;
  }
  __syncthreads();

  for (int lay = 0; lay < 3; lay++){
    const u16*  WlP = attnWP + (long)lay * 4 * 65536;
    const float* Bl = attnB + lay * 1024;
    const u16*  F1  = f1P + (long)lay * 524288;
    const u16*  F2  = f2P + (long)lay * 524288;

    bf16v8 qf[2], kf[2], pa[2];
    {
      bf16v8 wr_[8][2];
      #pragma unroll
      for (int ks = 0; ks < 8; ks++)
        #pragma unroll
        for (int ct = 0; ct < 2; ct++)
          wr_[ks][ct] = __builtin_bit_cast(bf16v8, *(const uint4*)(WlP + ((w*2+ct)*8 + ks)*512 + l*8));
      f32x4 acc[2][2] = {};
      __builtin_amdgcn_s_setprio(1);
      #pragma unroll
      for (int ks = 0; ks < 8; ks++){
        bf16v8 a0 = __builtin_bit_cast(bf16v8, *(const uint4*)&X[fr*264 + ks*32 + ko]);
        bf16v8 a1 = __builtin_bit_cast(bf16v8, *(const uint4*)&X[(16+fr)*264 + ks*32 + ko]);
        #pragma unroll
        for (int ct = 0; ct < 2; ct++){
          acc[0][ct] = __builtin_amdgcn_mfma_f32_16x16x32_bf16(a0, wr_[ks][ct], acc[0][ct], 0, 0, 0);
          acc[1][ct] = __builtin_amdgcn_mfma_f32_16x16x32_bf16(a1, wr_[ks][ct], acc[1][ct], 0, 0, 0);
        }
      }
      __builtin_amdgcn_s_setprio(0);
      #pragma unroll
      for (int rt = 0; rt < 2; rt++)
        #pragma unroll
        for (int ct = 0; ct < 2; ct++){
          const float bb = Bl[w*32 + ct*16 + fr];
          #pragma unroll
          for (int j = 0; j < 4; j++)
            Sw[(rt*16 + hi4 + j)*40 + ct*16 + fr] = f2bf(acc[rt][ct][j] + bb);
        }
      qf[0] = __builtin_bit_cast(bf16v8, *(const uint4*)&Sw[fr*40 + ko]);
      qf[1] = __builtin_bit_cast(bf16v8, *(const uint4*)&Sw[(16+fr)*40 + ko]);
    }
    {
      bf16v8 wr_[8][2];
      #pragma unroll
      for (int ks = 0; ks < 8; ks++)
        #pragma unroll
        for (int ct = 0; ct < 2; ct++)
          wr_[ks][ct] = __builtin_bit_cast(bf16v8, *(const uint4*)(WlP + 65536 + ((w*2+ct)*8 + ks)*512 + l*8));
      f32x4 acc[2][2] = {};
      __builtin_amdgcn_s_setprio(1);
      #pragma unroll
      for (int ks = 0; ks < 8; ks++){
        bf16v8 a0 = __builtin_bit_cast(bf16v8, *(const uint4*)&X[fr*264 + ks*32 + ko]);
        bf16v8 a1 = __builtin_bit_cast(bf16v8, *(const uint4*)&X[(16+fr)*264 + ks*32 + ko]);
        #pragma unroll
        for (int ct = 0; ct < 2; ct++){
          acc[0][ct] = __builtin_amdgcn_mfma_f32_16x16x32_bf16(a0, wr_[ks][ct], acc[0][ct], 0, 0, 0);
          acc[1][ct] = __builtin_amdgcn_mfma_f32_16x16x32_bf16(a1, wr_[ks][ct], acc[1][ct], 0, 0, 0);
        }
      }
      __builtin_amdgcn_s_setprio(0);
      #pragma unroll
      for (int rt = 0; rt < 2; rt++)
        #pragma unroll
        for (int ct = 0; ct < 2; ct++){
          const float bb = Bl[256 + w*32 + ct*16 + fr];
          #pragma unroll
          for (int j = 0; j < 4; j++)
            Sw[(rt*16 + hi4 + j)*40 + ct*16 + fr] = f2bf(acc[rt][ct][j] + bb);
        }
      kf[0] = __builtin_bit_cast(bf16v8, *(const uint4*)&Sw[fr*40 + ko]);
      kf[1] = __builtin_bit_cast(bf16v8, *(const uint4*)&Sw[(16+fr)*40 + ko]);
    }
    {
      f32x4 accS[2][2];
      #pragma unroll
      for (int rt = 0; rt < 2; rt++)
        #pragma unroll
        for (int nt = 0; nt < 2; nt++){
          f32x4 z = {0.f,0.f,0.f,0.f};
          accS[rt][nt] = __builtin_amdgcn_mfma_f32_16x16x32_bf16(qf[rt], kf[nt], z, 0, 0, 0);
        }
      const float SCALE = 0.17677669529663687f;
      const bool v1 = (fr < 7);
      #pragma unroll
      for (int rt = 0; rt < 2; rt++){
        #pragma unroll
        for (int j = 0; j < 4; j++){
          float x0 = accS[rt][0][j] * SCALE;
          float x1 = v1 ? accS[rt][1][j] * SCALE : -1e30f;
          float mx = fmaxf(x0, x1);
          #pragma unroll
          for (int o = 1; o < 16; o <<= 1) mx = fmaxf(mx, __shfl_xor(mx, o));
          float e0 = __expf(x0 - mx);
          float e1 = v1 ? __expf(x1 - mx) : 0.0f;
          float sum = e0 + e1;
          #pragma unroll
          for (int o = 1; o < 16; o <<= 1) sum += __shfl_xor(sum, o);
          const float inv = 1.0f / sum;
          const int row = rt*16 + hi4 + j;
          Sw[row*40 + fr]      = f2bf(e0 * inv);
          Sw[row*40 + 16 + fr] = f2bf(e1 * inv);
        }
      }
      pa[0] = __builtin_bit_cast(bf16v8, *(const uint4*)&Sw[fr*40 + ko]);
      pa[1] = __builtin_bit_cast(bf16v8, *(const uint4*)&Sw[(16+fr)*40 + ko]);
    }
    {
      bf16v8 wr_[8][2];
      #pragma unroll
      for (int ks = 0; ks < 8; ks++)
        #pragma unroll
        for (int ct = 0; ct < 2; ct++)
          wr_[ks][ct] = __builtin_bit_cast(bf16v8, *(const uint4*)(WlP + 131072 + ((w*2+ct)*8 + ks)*512 + l*8));
      f32x4 acc[2][2] = {};
      __builtin_amdgcn_s_setprio(1);
      #pragma unroll
      for (int ks = 0; ks < 8; ks++){
        bf16v8 a0 = __builtin_bit_cast(bf16v8, *(const uint4*)&X[fr*264 + ks*32 + ko]);
        bf16v8 a1 = __builtin_bit_cast(bf16v8, *(const uint4*)&X[(16+fr)*264 + ks*32 + ko]);
        #pragma unroll
        for (int ct = 0; ct < 2; ct++){
          acc[0][ct] = __builtin_amdgcn_mfma_f32_16x16x32_bf16(a0, wr_[ks][ct], acc[0][ct], 0, 0, 0);
          acc[1][ct] = __builtin_amdgcn_mfma_f32_16x16x32_bf16(a1, wr_[ks][ct], acc[1][ct], 0, 0, 0);
        }
      }
      __builtin_amdgcn_s_setprio(0);
      #pragma unroll
      for (int rt = 0; rt < 2; rt++)
        #pragma unroll
        for (int ct = 0; ct < 2; ct++){
          const float bb = Bl[512 + w*32 + ct*16 + fr];
          u16* dst = &Sw[(ct*16 + fr)*40 + rt*16 + hi4];
          #pragma unroll
          for (int j = 0; j < 4; j++)
            dst[j] = f2bf(acc[rt][ct][j] + bb);
        }
      bf16v8 vb0 = __builtin_bit_cast(bf16v8, *(const uint4*)&Sw[fr*40 + ko]);
      bf16v8 vb1 = __builtin_bit_cast(bf16v8, *(const uint4*)&Sw[(16+fr)*40 + ko]);
      f32x4 accO[2][2];
      #pragma unroll
      for (int rt = 0; rt < 2; rt++){
        f32x4 z = {0.f,0.f,0.f,0.f};
        accO[rt][0] = __builtin_amdgcn_mfma_f32_16x16x32_bf16(pa[rt], vb0, z, 0, 0, 0);
        accO[rt][1] = __builtin_amdgcn_mfma_f32_16x16x32_bf16(pa[rt], vb1, z, 0, 0, 0);
      }
      #pragma unroll
      for (int rt = 0; rt < 2; rt++)
        #pragma unroll
        for (int nt = 0; nt < 2; nt++)
          #pragma unroll
          for (int j = 0; j < 4; j++)
            Y[(rt*16 + hi4 + j)*264 + w*32 + nt*16 + fr] = f2bf(accO[rt][nt][j]);
    }
    __syncthreads();

    {
      bf16v8 wr_[8][2];
      #pragma unroll
      for (int ks = 0; ks < 8; ks++)
        #pragma unroll
        for (int ct = 0; ct < 2; ct++)
          wr_[ks][ct] = __builtin_bit_cast(bf16v8, *(const uint4*)(WlP + 196608 + ((w*2+ct)*8 + ks)*512 + l*8));
      f32x4 acc[2][2] = {};
      __builtin_amdgcn_s_setprio(1);
      #pragma unroll
      for (int ks = 0; ks < 8; ks++){
        bf16v8 a0 = __builtin_bit_cast(bf16v8, *(const uint4*)&Y[fr*264 + ks*32 + ko]);
        bf16v8 a1 = __builtin_bit_cast(bf16v8, *(const uint4*)&Y[(16+fr)*264 + ks*32 + ko]);
        #pragma unroll
        for (int ct = 0; ct < 2; ct++){
          acc[0][ct] = __builtin_amdgcn_mfma_f32_16x16x32_bf16(a0, wr_[ks][ct], acc[0][ct], 0, 0, 0);
          acc[1][ct] = __builtin_amdgcn_mfma_f32_16x16x32_bf16(a1, wr_[ks][ct], acc[1][ct], 0, 0, 0);
        }
      }
      __builtin_amdgcn_s_setprio(0);
      float val[2][2][4];
      #pragma unroll
      for (int ct = 0; ct < 2; ct++){
        const int col = w*32 + ct*16 + fr;
        const float bb = Bl[768 + col];
        #pragma unroll
        for (int rt = 0; rt < 2; rt++)
          #pragma unroll
          for (int j = 0; j < 4; j++)
            val[rt][ct][j] = acc[rt][ct][j] + bb + bf2f(X[(rt*16 + hi4 + j)*264 + col]);
      }
      #pragma unroll
      for (int rt = 0; rt < 2; rt++)
        #pragma unroll
        for (int j = 0; j < 4; j++){
          float s1 = val[rt][0][j] + val[rt][1][j];
          float s2 = val[rt][0][j]*val[rt][0][j] + val[rt][1][j]*val[rt][1][j];
          #pragma unroll
          for (int o = 1; o < 16; o <<= 1){ s1 += __shfl_xor(s1, o); s2 += __shfl_xor(s2, o); }
          if (fr == 0){
            const int row = rt*16 + hi4 + j;
            st1[row*8 + w] = s1; st2[row*8 + w] = s2;
          }
        }
      __syncthreads();
      if (tid < 32){
        float s1 = 0.f, s2 = 0.f;
        #pragma unroll
        for (int k = 0; k < 8; k++){ s1 += st1[tid*8 + k]; s2 += st2[tid*8 + k]; }
        const float mu = s1 * (1.0f/256.0f);
        const float var = s2 * (1.0f/256.0f) - mu*mu;
        muA[tid] = mu; rsA[tid] = rsqrtf(var + 1e-5f);
      }
      __syncthreads();
      #pragma unroll
      for (int ct = 0; ct < 2; ct++){
        const int col = w*32 + ct*16 + fr;
        const float lw = lnS[lay*512 + col], lb = lnB[lay*512 + col];
        #pragma unroll
        for (int rt = 0; rt < 2; rt++)
          #pragma unroll
          for (int j = 0; j < 4; j++){
            const int row = rt*16 + hi4 + j;
            X[row*264 + col] = f2bf((val[rt][ct][j] - muA[row]) * rsA[row] * lw + lb);
          }
      }
      __syncthreads();
    }

    {
      f32x4 acc2[2][2] = {};
      for (int c = 0; c < 8; c++){
        u16* Yc = Yb + (c & 1) * 8448;
        bf16v8 w1r[8][2];
        #pragma unroll
        for (int ks = 0; ks < 8; ks++)
          #pragma unroll
          for (int ct = 0; ct < 2; ct++)
            w1r[ks][ct] = __builtin_bit_cast(bf16v8, *(const uint4*)(F1 + (long)((c*16 + w*2 + ct)*8 + ks)*512 + l*8));
        f32x4 acc1[2][2] = {};
        __builtin_amdgcn_s_setprio(1);
        #pragma unroll
        for (int ks = 0; ks < 8; ks++){
          bf16v8 a0 = __builtin_bit_cast(bf16v8, *(const uint4*)&X[fr*264 + ks*32 + ko]);
          bf16v8 a1 = __builtin_bit_cast(bf16v8, *(const uint4*)&X[(16+fr)*264 + ks*32 + ko]);
          #pragma unroll
          for (int ct = 0; ct < 2; ct++){
            acc1[0][ct] = __builtin_amdgcn_mfma_f32_16x16x32_bf16(a0, w1r[ks][ct], acc1[0][ct], 0, 0, 0);
            acc1[1][ct] = __builtin_amdgcn_mfma_f32_16x16x32_bf16(a1, w1r[ks][ct], acc1[1][ct], 0, 0, 0);
          }
        }
        __builtin_amdgcn_s_setprio(0);
        bf16v8 w2r[8][2];
        #pragma unroll
        for (int ks = 0; ks < 8; ks++)
          #pragma unroll
          for (int ct = 0; ct < 2; ct++)
            w2r[ks][ct] = __builtin_bit_cast(bf16v8, *(const uint4*)(F2 + (long)((w*2+ct)*64 + c*8 + ks)*512 + l*8));
        #pragma unroll
        for (int ct = 0; ct < 2; ct++){
          const float bb = f1B[lay*2048 + c*256 + w*32 + ct*16 + fr];
          #pragma unroll
          for (int rt = 0; rt < 2; rt++)
            #pragma unroll
            for (int j = 0; j < 4; j++)
              Yc[(rt*16 + hi4 + j)*264 + w*32 + ct*16 + fr] = f2bf(fmaxf(acc1[rt][ct][j] + bb, 0.0f));
        }
        __syncthreads();
        __builtin_amdgcn_s_setprio(1);
        #pragma unroll
        for (int ks = 0; ks < 8; ks++){
          bf16v8 a0 = __builtin_bit_cast(bf16v8, *(const uint4*)&Yc[fr*264 + ks*32 + ko]);
          bf16v8 a1 = __builtin_bit_cast(bf16v8, *(const uint4*)&Yc[(16+fr)*264 + ks*32 + ko]);
          #pragma unroll
          for (int ct = 0; ct < 2; ct++){
            acc2[0][ct] = __builtin_amdgcn_mfma_f32_16x16x32_bf16(a0, w2r[ks][ct], acc2[0][ct], 0, 0, 0);
            acc2[1][ct] = __builtin_amdgcn_mfma_f32_16x16x32_bf16(a1, w2r[ks][ct], acc2[1][ct], 0, 0, 0);
          }
        }
        __builtin_amdgcn_s_setprio(0);
      }
      __syncthreads();
      float val[2][2][4];
      #pragma unroll
      for (int ct = 0; ct < 2; ct++){
        const int col = w*32 + ct*16 + fr;
        const float bb = f2B[lay*256 + col];
        #pragma unroll
        for (int rt = 0; rt < 2; rt++)
          #pragma unroll
          for (int j = 0; j < 4; j++)
            val[rt][ct][j] = acc2[rt][ct][j] + bb + bf2f(X[(rt*16 + hi4 + j)*264 + col]);
      }
      #pragma unroll
      for (int rt = 0; rt < 2; rt++)
        #pragma unroll
        for (int j = 0; j < 4; j++){
          float s1 = val[rt][0][j] + val[rt][1][j];
          float s2 = val[rt][0][j]*val[rt][0][j] + val[rt][1][j]*val[rt][1][j];
          #pragma unroll
          for (int o = 1; o < 16; o <<= 1){ s1 += __shfl_xor(s1, o); s2 += __shfl_xor(s2, o); }
          if (fr == 0){
            const int row = rt*16 + hi4 + j;
            st1[row*8 + w] = s1; st2[row*8 + w] = s2;
          }
        }
      __syncthreads();
      if (tid < 32){
        float s1 = 0.f, s2 = 0.f;
        #pragma unroll
        for (int k = 0; k < 8; k++){ s1 += st1[tid*8 + k]; s2 += st2[tid*8 + k]; }
        const float mu = s1 * (1.0f/256.0f);
        const float var = s2 * (1.0f/256.0f) - mu*mu;
        muA[tid] = mu; rsA[tid] = rsqrtf(var + 1e-5f);
      }
      __syncthreads();
      #pragma unroll
      for (int ct = 0; ct < 2; ct++){
        const int col = w*32 + ct*16 + fr;
        const float lw = lnS[lay*512 + 256 + col], lb = lnB[lay*512 + 256 + col];
        #pragma unroll
        for (int rt = 0; rt < 2; rt++)
          #pragma unroll
          for (int j = 0; j < 4; j++){
            const int row = rt*16 + hi4 + j;
            X[row*264 + col] = f2bf((val[rt][ct][j] - muA[row]) * rsA[row] * lw + lb);
          }
      }
      __syncthreads();
    }
  }

  for (int idx = tid; idx < 736; idx += 512){
    const int row = idx >> 5, c8 = (idx & 31) * 8;
    *(uint4*)(se + (tb + row)*256 + c8) = *(const uint4*)&X[row*264 + c8];
  }
}

// ---------- glob MLP stage 1
__global__ __launch_bounds__(256) void glob1_k(const float* __restrict__ xg, const float* __restrict__ w1,
                                               const float* __restrict__ b1, u16* __restrict__ h){
  int b = blockIdx.x, d = threadIdx.x;
  float s = b1[d];
  #pragma unroll
  for (int k = 0; k < 16; k++) s += xg[b*16 + k] * w1[k*256 + d];
  h[(long)b*256 + d] = f2bf(gelu_fast(s));
}

// ---------- event sequence fill
__global__ __launch_bounds__(64) void fill_se(u16* __restrict__ se, const float* __restrict__ cls_task,
                                              const u16* __restrict__ globo, const float* __restrict__ pos_emb,
                                              const float* __restrict__ empty_emb){
  int bt = blockIdx.x;
  int b = bt / NTOKE, tk = bt % NTOKE;
  int t = threadIdx.x;
  u16* d = se + (long)bt * D_MOD;
  #pragma unroll
  for (int j = 0; j < 4; j++){
    int c = t*4 + j;
    float v;
    if (tk < 7) v = cls_task[tk*D_MOD + c];
    else if (tk == 7) v = bf2f(globo[(long)b*D_MOD + c]) + pos_emb[c];
    else v = empty_emb[c] + pos_emb[(tk - 7)*D_MOD + c];
    d[c] = f2bf(v);
  }
}

// ---------- scatter module CLS into event sequence (+pos_emb)
__global__ __launch_bounds__(64) void scatter_mod(u16* __restrict__ se, const u16* __restrict__ seqc,
                                                  const int* __restrict__ m2e, const int* __restrict__ mpos,
                                                  const int* __restrict__ starts,
                                                  const float* __restrict__ pos_emb){
  int m = blockIdx.x, t = threadIdx.x;
  int e = m2e[m], p = mpos[m];
  const u16* src = seqc + ((long)starts[m] + m) * D_MOD;
  u16* dst = se + ((long)e * NTOKE + 8 + p) * D_MOD;
  const float* pe = pos_emb + (long)(1 + p) * D_MOD;
  #pragma unroll
  for (int j = 0; j < 4; j++){
    int c = t*4 + j;
    dst[c] = f2bf(bf2f(src[c]) + pe[c]);
  }
}

// ---------- heads
__global__ __launch_bounds__(64) void heads_k(const u16* __restrict__ se, const float* __restrict__ hw,
                                              const float* __restrict__ hb, float* __restrict__ out){
  int b = blockIdx.x, t = threadIdx.x;
  __shared__ float raw[16];
  if (t < 16){
    int tok = (t < 4) ? 0 : (t <= 8) ? (t - 3) : (t <= 11) ? 5 : 6;
    const u16* e = se + ((long)b * NTOKE + tok) * D_MOD;
    float s = hb[t];
    for (int d = 0; d < 256; d++) s += bf2f(e[d]) * hw[d*16 + t];
    raw[t] = s;
  }
  __syncthreads();
  if (t < 16){
    float v = raw[t];
    float r;
    if (t <= 8 || t == 12){
      r = fmaxf(v, 0.0f) + log1pf(__expf(-fabsf(v)));
    } else if (t <= 11){
      float n = sqrtf(raw[9]*raw[9] + raw[10]*raw[10] + raw[11]*raw[11]);
      r = v / fmaxf(n, 1e-12f);
    } else {
      float n = sqrtf(raw[13]*raw[13] + raw[14]*raw[14] + raw[15]*raw[15]);
      r = v / fmaxf(n, 1e-12f);
    }
    out[b*16 + t] = r;
  }
}

extern "C" void kernel_launch(void* const* d_in, const int* in_sizes, int n_in,
                              void* d_out, int out_size, void* d_ws, size_t ws_size,
                              hipStream_t stream){
  const float* feats      = (const float*)d_in[0];
  const float* coords     = (const float*)d_in[1];
  const int*   batch_ids  = (const int*)d_in[2];
  const int*   m2e        = (const int*)d_in[3];
  const int*   mpos       = (const int*)d_in[4];
  const float* x_glob     = (const float*)d_in[5];
  const float* cls_mod    = (const float*)d_in[6];
  const float* empty_emb  = (const float*)d_in[7];
  const float* cls_task   = (const float*)d_in[8];
  const float* pos_emb    = (const float*)d_in[9];
  const float* mod_attn_w = (const float*)d_in[10];
  const float* mod_attn_b = (const float*)d_in[11];
  const float* mod_rel    = (const float*)d_in[12];
  const float* mod_ln_s   = (const float*)d_in[13];
  const float* mod_ln_b   = (const float*)d_in[14];
  const float* mod_ffn_w1 = (const float*)d_in[15];
  const float* mod_ffn_b1 = (const float*)d_in[16];
  const float* mod_ffn_w2 = (const float*)d_in[17];
  const float* mod_ffn_b2 = (const float*)d_in[18];
  const float* glob_w1    = (const float*)d_in[19];
  const float* glob_b1    = (const float*)d_in[20];
  const float* glob_w2    = (const float*)d_in[21];
  const float* glob_b2    = (const float*)d_in[22];
  const float* evt_attn_w = (const float*)d_in[23];
  const float* evt_attn_b = (const float*)d_in[24];
  const float* evt_ln_s   = (const float*)d_in[25];
  const float* evt_ln_b   = (const float*)d_in[26];
  const float* evt_ffn_w1 = (const float*)d_in[27];
  const float* evt_ffn_b1 = (const float*)d_in[28];
  const float* evt_ffn_w2 = (const float*)d_in[29];
  const float* evt_ffn_b2 = (const float*)d_in[30];
  const float* head_w     = (const float*)d_in[31];
  const float* head_b     = (const float*)d_in[32];
  float* out = (float*)d_out;

  const int N = in_sizes[0] / 256;
  const int M = in_sizes[3];
  const int B = in_sizes[5] / 16;
  const long CROWS   = (long)M + N;                         // 54306
  const long CROWS_P = (((CROWS + 255) >> 8) << 8) + 256;   // pad to x256 + overrun guard
  const long TE  = (long)B * NTOKE;

  char* ws = (char*)d_ws;
  u16* modWT   = (u16*)ws;
  u16* evtWT   = modWT + 8L*65536;
  u16* modF1T  = evtWT + 12L*65536;
  u16* modF2T  = modF1T + 2L*262144;
  u16* evtF1T  = modF2T + 2L*262144;
  u16* evtF2T  = evtF1T + 3L*524288;
  u16* globW2T = evtF2T + 3L*524288;
  size_t off = 11468800;
  int* counts = (int*)(ws + off); off += 16*1024;
  int* starts = (int*)(ws + off); off += 16*1024;
  float* scc  = (float*)(ws + off); off += ((size_t)CROWS_P*12 + 255) & ~(size_t)255;
  u16* seqc   = (u16*)(ws + off); off += (size_t)CROWS_P * D_MOD * 2;
  off = (off + 255) & ~(size_t)255;
  const size_t OFF_BIG = off;
  u16* qkv   = (u16*)(ws + OFF_BIG);
  u16* attno = (u16*)(ws + OFF_BIG + (size_t)CROWS_P*768*2);
  u16* ffh   = (u16*)(ws + OFF_BIG);
  u16* se    = (u16*)(ws + OFF_BIG);
  u16* globh = (u16*)(ws + OFF_BIG + 12*1024*1024);
  u16* globo = (u16*)(ws + OFF_BIG + 13*1024*1024);
  u16* evtWP  = (u16*)(ws + OFF_BIG + 120L*1024*1024);
  u16* evtF1P = evtWP + 12L*65536;
  u16* evtF2P = evtF1P + 3L*524288;

  prep_all<<<5440, 256, 0, stream>>>(mod_attn_w, evt_attn_w, mod_ffn_w1, mod_ffn_w2,
                                     evt_ffn_w1, evt_ffn_w2, glob_w2,
                                     modWT, evtWT, modF1T, modF2T, evtF1T, evtF2T, globW2T,
                                     evtWP, evtF1P, evtF2P);

  hipMemsetAsync(counts, 0, (size_t)M*4, stream);
  hipMemsetAsync(scc, 0, (size_t)CROWS_P*12, stream);
  hipMemsetAsync(seqc + CROWS*D_MOD, 0, (size_t)(CROWS_P - CROWS)*D_MOD*2, stream);
  hipMemsetAsync(attno + CROWS*D_MOD, 0, (size_t)(CROWS_P - CROWS)*D_MOD*2, stream);
  count_k<<<(N + 255)/256, 256, 0, stream>>>(batch_ids, counts, N);
  scan_k<<<1, 1024, 0, stream>>>(counts, starts, M);
  cls_fill<<<M, 64, 0, stream>>>(seqc, cls_mod, starts);
  scatter_k<<<N, 64, 0, stream>>>(feats, coords, batch_ids, seqc, scc);

  const int RB = (int)(CROWS_P / 256);
  const int RB2 = (int)(CROWS_P / 128);
  for (int l = 0; l < 2; l++){
    gemm256<0><<<dim3(6, RB), 512, 0, stream>>>(seqc, modWT + (long)l*4*65536,
        mod_attn_b + l*1024, nullptr, qkv, 256, 768);
    mod_attn_all<<<dim3(M, NHEAD), 256, 0, stream>>>(qkv, scc, mod_rel + l*24, counts, starts, attno);
    gemm_ln<<<dim3(1, RB2), 512, 0, stream>>>(attno, modWT + ((long)l*4+3)*65536,
        mod_attn_b + l*1024 + 768, seqc, seqc, 256,
        mod_ln_s + (l*2)*256, mod_ln_b + (l*2)*256);
    gemm256<1><<<dim3(8, RB), 512, 0, stream>>>(seqc, modF1T + (long)l*262144,
        mod_ffn_b1 + l*1024, nullptr, ffh, 256, 1024);
    gemm256<3><<<dim3(2, RB), 512, 0, stream>>>(ffh, modF2T + (long)l*262144,
        mod_ffn_b2 + l*256, seqc, seqc, 1024, 256);
    ln_k<<<(int)((CROWS + 3)/4), 256, 0, stream>>>(seqc, mod_ln_s + (l*2+1)*256, mod_ln_b + (l*2+1)*256, CROWS);
  }

  hipMemsetAsync(globh, 0, 256*256*2, stream);
  glob1_k<<<B, 256, 0, stream>>>(x_glob, glob_w1, glob_b1, globh);
  gemm256<0><<<dim3(2, 1), 512, 0, stream>>>(globh, globW2T, glob_b2, nullptr, globo, 256, 256);
  fill_se<<<(int)TE, 64, 0, stream>>>(se, cls_task, globo, pos_emb, empty_emb);
  scatter_mod<<<M, 64, 0, stream>>>(se, seqc, m2e, mpos, starts, pos_emb);

  evt_fused<<<B, 512, 0, stream>>>(se, evtWP, evt_attn_b, evtF1P, evt_ffn_b1,
                                   evtF2P, evt_ffn_b2, evt_ln_s, evt_ln_b);

  heads_k<<<B, 64, 0, stream>>>(se, head_w, head_b, out);
}

// Round 25
// 809.305 us; speedup vs baseline: 1.0535x; 1.0204x over previous
//
#include <hip/hip_runtime.h>
#include <hip/hip_bf16.h>
#include <math.h>

typedef unsigned short u16;
typedef unsigned int u32;
typedef __bf16 bf16v8 __attribute__((ext_vector_type(8)));
typedef _Float16 f16v8 __attribute__((ext_vector_type(8)));
typedef __attribute__((ext_vector_type(4))) float f32x4;

#define D_MOD 256
#define NHEAD 8
#define DHEAD 32
#define SEQL 97
#define NTOKE 23

__device__ __forceinline__ float bf2f(u16 u){
  union { unsigned int i; float f; } x; x.i = ((unsigned int)u) << 16; return x.f;
}
__device__ __forceinline__ u16 f2bf(float f){
  return __builtin_bit_cast(u16, (__bf16)f);
}
__device__ __forceinline__ float gelu_fast(float v){
  float z = v * 0.70710678118654752f;
  float az = fabsf(z);
  float t = __builtin_amdgcn_rcpf(fmaf(0.3275911f, az, 1.0f));
  float p = t*(0.254829592f + t*(-0.284496736f + t*(1.421413741f + t*(-1.453152027f + t*1.061405429f))));
  float e = __expf(-z*z);
  float y = 1.0f - p*e;
  float erfz = copysignf(y, z);
  return 0.5f * v * (1.0f + erfz);
}
__device__ __forceinline__ void gld16(const void* g, void* l){
  __builtin_amdgcn_global_load_lds((const __attribute__((address_space(1))) void*)g,
                                   (__attribute__((address_space(3))) void*)l, 16, 0, 0);
}

// ---------- ONE-SHOT weight prep (r19-exact): transpose + event fragment-packing
__global__ __launch_bounds__(256) void prep_all(
    const float* __restrict__ aw, const float* __restrict__ ew,
    const float* __restrict__ f1m, const float* __restrict__ f2m,
    const float* __restrict__ f1e, const float* __restrict__ f2e,
    const float* __restrict__ gw2,
    u16* __restrict__ modWT, u16* __restrict__ evtWT,
    u16* __restrict__ modF1T, u16* __restrict__ modF2T,
    u16* __restrict__ evtF1T, u16* __restrict__ evtF2T,
    u16* __restrict__ globW2T,
    u16* __restrict__ WP, u16* __restrict__ F1P, u16* __restrict__ F2P)
{
  const int id = blockIdx.x;
  const float* src; u16* dst; u16* pk = nullptr; int K, N, kx, nx, t; long sS, dS;
  if (id < 512)      { t = id;        src = aw;  dst = modWT;   K=256;  N=256;  kx=8;  nx=8;  sS=65536;  dS=65536;  }
  else if (id < 1280){ t = id - 512;  src = ew;  dst = evtWT;   K=256;  N=256;  kx=8;  nx=8;  sS=65536;  dS=65536;  pk = WP;  }
  else if (id < 1792){ t = id - 1280; src = f1m; dst = modF1T;  K=256;  N=1024; kx=8;  nx=32; sS=262144; dS=262144; }
  else if (id < 2304){ t = id - 1792; src = f2m; dst = modF2T;  K=1024; N=256;  kx=32; nx=8;  sS=262144; dS=262144; }
  else if (id < 3840){ t = id - 2304; src = f1e; dst = evtF1T;  K=256;  N=2048; kx=8;  nx=64; sS=524288; dS=524288; pk = F1P; }
  else if (id < 5376){ t = id - 3840; src = f2e; dst = evtF2T;  K=2048; N=256;  kx=64; nx=8;  sS=524288; dS=524288; pk = F2P; }
  else               { t = id - 5376; src = gw2; dst = globW2T; K=256;  N=256;  kx=8;  nx=8;  sS=65536;  dS=65536;  }
  const int per = kx * nx;
  const int z = t / per, rem = t % per;
  const int k0 = (rem % kx) * 32, n0 = (rem / kx) * 32;
  src += (long)z * sS; dst += (long)z * dS;
  __shared__ float tt[32][33];
  const int tx = threadIdx.x & 31, ty = threadIdx.x >> 5;
  #pragma unroll
  for (int r = ty; r < 32; r += 8)
    tt[r][tx] = src[(long)(k0 + r) * N + n0 + tx];
  __syncthreads();
  #pragma unroll
  for (int r = ty; r < 32; r += 8)
    dst[(long)(n0 + r) * K + k0 + tx] = f2bf(tt[tx][r]);
  if (pk && threadIdx.x < 128){
    const int q = threadIdx.x >> 6, l = threadIdx.x & 63;
    const int nb = (n0 >> 4) + q, kb = k0 >> 5;
    const int c = q*16 + (l & 15);
    const int klb = (l >> 4) * 8;
    const long fragi = (long)nb * (K/32) + kb;
    u16 frag[8];
    #pragma unroll
    for (int e = 0; e < 8; e++) frag[e] = f2bf(tt[klb + e][c]);
    u16* d = pk + (long)z * (long)N * K + (fragi*64 + l)*8;
    *(uint4*)d = *(const uint4*)frag;
  }
}

// ---------- counts / scan / scatter
__global__ void count_k(const int* __restrict__ bids, int* __restrict__ counts, int n){
  int i = blockIdx.x * blockDim.x + threadIdx.x;
  if (i < n) atomicAdd(&counts[bids[i]], 1);
}

__global__ void scan_k(const int* __restrict__ counts, int* __restrict__ starts, int M){
  __shared__ int buf[1024];
  int t = threadIdx.x;
  int v = (t < M) ? counts[t] : 0;
  buf[t] = v;
  __syncthreads();
  for (int o = 1; o < 1024; o <<= 1){
    int x = (t >= o) ? buf[t - o] : 0;
    __syncthreads();
    buf[t] += x;
    __syncthreads();
  }
  if (t < M) starts[t] = buf[t] - v;
}

__global__ __launch_bounds__(64) void cls_fill(u16* __restrict__ seqc, const float* __restrict__ cls_mod,
                                               const int* __restrict__ starts){
  int m = blockIdx.x, t = threadIdx.x;
  long row = (long)starts[m] + m;
  const float4 v = *(const float4*)(cls_mod + t * 4);
  u16* d = seqc + row * D_MOD + t * 4;
  d[0] = f2bf(v.x); d[1] = f2bf(v.y); d[2] = f2bf(v.z); d[3] = f2bf(v.w);
}

__global__ __launch_bounds__(64) void scatter_k(const float* __restrict__ feats, const float* __restrict__ coords,
                          const int* __restrict__ bids, u16* __restrict__ seqc, float* __restrict__ scc){
  int i = blockIdx.x, t = threadIdx.x;
  long row = (long)i + bids[i] + 1;
  const float4 v = *(const float4*)(feats + (long)i * D_MOD + t * 4);
  u16* d = seqc + row * D_MOD + t * 4;
  d[0] = f2bf(v.x); d[1] = f2bf(v.y); d[2] = f2bf(v.z); d[3] = f2bf(v.w);
  if (t < 3) scc[row * 3 + t] = coords[(long)i * 3 + t];
}

// ---------- 256x128 bf16 MFMA GEMM, r20 geometry, TRIPLE-BUFFERED half-tile
// pipeline with counted vmcnt: loads for half h+1 stay in flight across the
// barrier (vmcnt(3)), never drained to 0 in the main loop. 3 x 24KB = 72KB LDS.
template<int EPI> // 0 none, 1 gelu, 2 relu, 3 +resid
__global__ __launch_bounds__(512) void gemm256(
    const u16* __restrict__ A, const u16* __restrict__ Wt,
    const float* __restrict__ bias, const u16* __restrict__ resid,
    u16* __restrict__ C, int K, int N)
{
  __shared__ __align__(16) char smemraw[73728];   // 3 bufs: A-half [256][32]=16KB + B-half [128][32]=8KB
  float* stg = (float*)smemraw;                   // epilogue [32][132] f32 (16.9KB)

  const int tid = threadIdx.x;
  const int w = tid >> 6, l = tid & 63;
  const int wr = w >> 1, wc = w & 1;

  const long nwg = (long)gridDim.x * gridDim.y;
  const long orig = (long)blockIdx.y * gridDim.x + blockIdx.x;
  const long q = nwg >> 3, r = nwg & 7;
  const long xcd = orig & 7, idx = orig >> 3;
  const long swz = (xcd < r ? xcd * (q + 1) : r * (q + 1) + (xcd - r) * q) + idx;
  const int colb = (int)(swz % gridDim.x);
  const long rowb = swz / gridDim.x;
  const long row0 = rowb * 256;
  const int col0 = colb * 128;

  const int fr = l & 15;
  const int ko = (l >> 4) * 8;
  f32x4 acc[4][4] = {};

  // per-thread staging addresses (one 32-wide half-tile: 2x A gld16 + 1x B gld16)
  const int sA1 = 512 + tid;
  const long arow0 = row0 + (tid >> 2), arow1 = row0 + (sA1 >> 2);
  const int ac0 = (tid & 3) * 8, ac1 = (sA1 & 3) * 8;
  const long brow = col0 + (tid >> 2);
  const int bc0 = (tid & 3) * 8;
  const int ldsA0 = (0*512 + w*64) * 8;   // u16 offsets within a buffer
  const int ldsA1 = (1*512 + w*64) * 8;
  const int ldsB0 = (w*64) * 8;

  const int NH = K >> 5;                  // 32-wide half-steps

  { // prologue: stage half 0 into buf 0
    u16* bufA = (u16*)smemraw;
    u16* bufB = (u16*)(smemraw + 16384);
    gld16(A  + arow0 * K + ac0, bufA + ldsA0);
    gld16(A  + arow1 * K + ac1, bufA + ldsA1);
    gld16(Wt + brow  * K + bc0, bufB + ldsB0);
  }

  int cb = 0, nb = 1;
  for (int h = 0; h < NH; h++){
    if (h + 1 < NH){
      const int kc = (h + 1) * 32;
      u16* bufA = (u16*)(smemraw + nb * 24576);
      u16* bufB = (u16*)(smemraw + nb * 24576 + 16384);
      gld16(A  + arow0 * K + kc + ac0, bufA + ldsA0);
      gld16(A  + arow1 * K + kc + ac1, bufA + ldsA1);
      gld16(Wt + brow  * K + kc + bc0, bufB + ldsB0);
      asm volatile("s_waitcnt vmcnt(3)" ::: "memory");   // own half-h loads landed
    } else {
      asm volatile("s_waitcnt vmcnt(0)" ::: "memory");
    }
    __builtin_amdgcn_s_barrier();                        // all waves' half-h loads landed
    __builtin_amdgcn_sched_barrier(0);
    const u16* cA = (const u16*)(smemraw + cb * 24576);
    const u16* cB = (const u16*)(smemraw + cb * 24576 + 16384);
    bf16v8 af[4], bfv[4];
    #pragma unroll
    for (int mi = 0; mi < 4; mi++)
      af[mi] = __builtin_bit_cast(bf16v8, *(const uint4*)(cA + (wr*64 + mi*16 + fr)*32 + ko));
    #pragma unroll
    for (int ni = 0; ni < 4; ni++)
      bfv[ni] = __builtin_bit_cast(bf16v8, *(const uint4*)(cB + (wc*64 + ni*16 + fr)*32 + ko));
    #pragma unroll
    for (int mi = 0; mi < 4; mi++)
      #pragma unroll
      for (int ni = 0; ni < 4; ni++)
        acc[mi][ni] = __builtin_amdgcn_mfma_f32_16x16x32_bf16(af[mi], bfv[ni], acc[mi][ni], 0, 0, 0);
    cb = nb; nb = (nb == 2) ? 0 : nb + 1;
  }

  // ---- epilogue: 8 passes of 32 rows (r20-exact); staged f32 -> coalesced stores
  const int rq = (l >> 4) * 4;
  #pragma unroll
  for (int p = 0; p < 8; p++){
    __syncthreads();
    if (wr == (p >> 1)){
      #pragma unroll
      for (int mm = 0; mm < 2; mm++){
        const int mi = (p & 1) * 2 + mm;
        #pragma unroll
        for (int ni = 0; ni < 4; ni++){
          const int coll = wc*64 + ni*16 + fr;
          const float bb = bias[col0 + coll];
          #pragma unroll
          for (int j = 0; j < 4; j++){
            float v = acc[mi][ni][j] + bb;
            if (EPI == 1) v = gelu_fast(v);
            if (EPI == 2) v = fmaxf(v, 0.0f);
            stg[(mm*16 + rq + j) * 132 + coll] = v;
          }
        }
      }
    }
    __syncthreads();
    {
      const int rowl = tid >> 4;           // 512 slots: 32 rows x 16 col8
      const int cs = (tid & 15) * 8;
      const long gbase = (row0 + p*32 + rowl) * (long)N + col0 + cs;
      float4 lo = *(const float4*)(stg + rowl*132 + cs);
      float4 hi = *(const float4*)(stg + rowl*132 + cs + 4);
      float vv[8] = {lo.x, lo.y, lo.z, lo.w, hi.x, hi.y, hi.z, hi.w};
      if (EPI == 3){
        uint4 rv = *(const uint4*)(resid + gbase);
        const u16* rp = (const u16*)&rv;
        #pragma unroll
        for (int e = 0; e < 8; e++) vv[e] += bf2f(rp[e]);
      }
      uint4 ov;
      u16* op = (u16*)&ov;
      #pragma unroll
      for (int e = 0; e < 8; e++) op[e] = f2bf(vv[e]);
      *(uint4*)(C + gbase) = ov;
    }
  }
}

// ---------- module attention body (r9-exact math), NT = #16-key-tiles, static bounds
template<int NT>
__device__ __forceinline__ void attn_body(
    char* __restrict__ smemRaw,
    const u16* __restrict__ qkv, const float* __restrict__ scc,
    const float* __restrict__ rel, const int S, const long base,
    u16* __restrict__ out)
{
  constexpr int KS  = (NT + 1) / 2;
  constexpr int NK  = NT * 16;
  constexpr int STR = (KS * 32 <= 64) ? 64 : 128;
  constexpr int PBYTES = (NK * STR * 2 > NK * 132) ? NK * STR * 2 : NK * 132;
  u16* Pb = (u16*)smemRaw;
  u16* Vt = (u16*)(smemRaw + PBYTES);
  float* pj = (float*)(smemRaw + PBYTES + 32 * STR * 2);

  const int h = blockIdx.y;
  const int tid = threadIdx.x, w = tid >> 6, l = tid & 63;
  const int fr = l & 15, ko = (l >> 4) * 8;

  if (tid < NK){
    float v = 1e30f;
    if (tid < S){
      const float* s3 = scc + (base + tid) * 3;
      v = s3[0]*rel[h*3] + s3[1]*rel[h*3+1] + s3[2]*rel[h*3+2];
    }
    pj[tid] = v;
  }
  for (int idx = tid; idx < NK*32; idx += 256){
    int key = idx >> 5, d = idx & 31;
    float v = bf2f(qkv[(base + key)*768 + 512 + h*32 + d]);
    v = fminf(fmaxf(v, -60000.0f), 60000.0f);
    _Float16 hv = (_Float16)v;
    Vt[d*STR + (key ^ ((d & 7) << 3))] = __builtin_bit_cast(u16, hv);
  }
  for (int idx = tid; idx < 32*16; idx += 256){
    int d = idx >> 4, c = NK + (idx & 15);
    Vt[d*STR + (c ^ ((d & 7) << 3))] = 0;
  }
  for (int idx = tid; idx < NK*16; idx += 256){
    int row = idx >> 4, c = NK + (idx & 15);
    Pb[row*STR + (c ^ ((row & 7) << 3))] = 0;
  }
  __syncthreads();

  f32x4 accs[2][NT];
  bf16v8 kf[NT];
  #pragma unroll
  for (int nt = 0; nt < NT; nt++)
    kf[nt] = __builtin_bit_cast(bf16v8, *(const uint4*)(qkv + (base + nt*16 + fr)*768 + 256 + h*32 + ko));
  #pragma unroll
  for (int rr2 = 0; rr2 < 2; rr2++){
    const int rt = w + rr2*4;
    if (rt > NT - 1) break;
    bf16v8 qf = __builtin_bit_cast(bf16v8, *(const uint4*)(qkv + (base + rt*16 + fr)*768 + h*32 + ko));
    #pragma unroll
    for (int nt = 0; nt < NT; nt++){
      f32x4 z = {0.f, 0.f, 0.f, 0.f};
      accs[rr2][nt] = __builtin_amdgcn_mfma_f32_16x16x32_bf16(qf, kf[nt], z, 0, 0, 0);
    }
  }

  float pjr[NT];
  #pragma unroll
  for (int nt = 0; nt < NT; nt++) pjr[nt] = pj[nt*16 + fr];
  const float SCALE = 0.17677669529663687f;
  #pragma unroll
  for (int rr2 = 0; rr2 < 2; rr2++){
    const int rt = w + rr2*4;
    if (rt > NT - 1) break;
    #pragma unroll
    for (int j = 0; j < 4; j++){
      float x[NT], mx = -1e30f;
      #pragma unroll
      for (int nt = 0; nt < NT; nt++){
        x[nt] = accs[rr2][nt][j] * SCALE - pjr[nt];
        mx = fmaxf(mx, x[nt]);
      }
      #pragma unroll
      for (int o = 1; o < 16; o <<= 1) mx = fmaxf(mx, __shfl_xor(mx, o));
      float sum = 0.f;
      #pragma unroll
      for (int nt = 0; nt < NT; nt++){
        x[nt] = __expf(x[nt] - mx);
        sum += x[nt];
      }
      #pragma unroll
      for (int o = 1; o < 16; o <<= 1) sum += __shfl_xor(sum, o);
      const float inv = 1.0f / sum;
      const int row = rt*16 + (l >> 4)*4 + j;
      #pragma unroll
      for (int nt = 0; nt < NT; nt++){
        _Float16 hp = (_Float16)(x[nt] * inv);
        Pb[row*STR + ((nt*16 + fr) ^ ((row & 7) << 3))] = __builtin_bit_cast(u16, hp);
      }
    }
  }
  __syncthreads();

  f32x4 accO[2][2];
  #pragma unroll
  for (int rr2 = 0; rr2 < 2; rr2++){
    const int rt = w + rr2*4;
    if (rt > NT - 1) break;
    #pragma unroll
    for (int nt = 0; nt < 2; nt++){
      f32x4 z = {0.f, 0.f, 0.f, 0.f};
      accO[rr2][nt] = z;
    }
    #pragma unroll
    for (int ks = 0; ks < KS; ks++){
      const int prow = rt*16 + fr;
      f16v8 pa = __builtin_bit_cast(f16v8, *(const uint4*)(Pb + prow*STR + ((ks*32 + ko) ^ ((prow & 7) << 3))));
      #pragma unroll
      for (int nt = 0; nt < 2; nt++){
        const int vrow = nt*16 + fr;
        f16v8 vb = __builtin_bit_cast(f16v8, *(const uint4*)(Vt + vrow*STR + ((ks*32 + ko) ^ ((vrow & 7) << 3))));
        accO[rr2][nt] = __builtin_amdgcn_mfma_f32_16x16x32_f16(pa, vb, accO[rr2][nt], 0, 0, 0);
      }
    }
  }
  __syncthreads();

  float* O = (float*)smemRaw;
  #pragma unroll
  for (int rr2 = 0; rr2 < 2; rr2++){
    const int rt = w + rr2*4;
    if (rt > NT - 1) break;
    #pragma unroll
    for (int nt = 0; nt < 2; nt++)
      #pragma unroll
      for (int j = 0; j < 4; j++)
        O[(rt*16 + (l>>4)*4 + j)*33 + nt*16 + fr] = accO[rr2][nt][j];
  }
  __syncthreads();
  for (int idx = tid; idx < NK*16; idx += 256){
    const int row = idx >> 4;
    if (row >= S) continue;
    const int c = (idx & 15) * 2;
    const float f0 = O[row*33 + c], f1 = O[row*33 + c + 1];
    u32 pk = (u32)f2bf(f0) | ((u32)f2bf(f1) << 16);
    *(u32*)(out + (base + row)*256 + h*32 + c) = pk;
  }
}

// ---------- single-launch bucketed attention
__global__ __launch_bounds__(256) void mod_attn_all(
    const u16* __restrict__ qkv, const float* __restrict__ scc,
    const float* __restrict__ rel, const int* __restrict__ counts,
    const int* __restrict__ starts, u16* __restrict__ out)
{
  __shared__ __align__(16) char smem[37376];
  const int m = blockIdx.x;
  const int S = counts[m] + 1;
  const long base = (long)starts[m] + m;
  if (S <= 48)      attn_body<3>(smem, qkv, scc, rel, S, base, out);
  else if (S <= 80) attn_body<5>(smem, qkv, scc, rel, S, base, out);
  else              attn_body<7>(smem, qkv, scc, rel, S, base, out);
}

// ---------- LayerNorm in-place, 4 rows per block
__global__ __launch_bounds__(256) void ln_k(u16* __restrict__ x, const float* __restrict__ s,
                                            const float* __restrict__ b, long nrows){
  const long row = (long)blockIdx.x * 4 + (threadIdx.x >> 6);
  if (row >= nrows) return;
  const int t = threadIdx.x & 63;
  u16* xr = x + row * D_MOD;
  uint2 rv = *(const uint2*)(xr + t * 4);
  float v0 = bf2f((u16)(rv.x & 0xffffu));
  float v1 = bf2f((u16)(rv.x >> 16));
  float v2 = bf2f((u16)(rv.y & 0xffffu));
  float v3 = bf2f((u16)(rv.y >> 16));
  float sum = v0 + v1 + v2 + v3;
  float sq  = v0*v0 + v1*v1 + v2*v2 + v3*v3;
  #pragma unroll
  for (int o = 32; o > 0; o >>= 1){
    sum += __shfl_xor(sum, o, 64);
    sq  += __shfl_xor(sq,  o, 64);
  }
  float mu = sum * (1.0f/256.0f);
  float var = sq * (1.0f/256.0f) - mu*mu;
  float rs = rsqrtf(var + 1e-5f);
  int c = t * 4;
  u16 o0 = f2bf((v0-mu)*rs*s[c+0]+b[c+0]);
  u16 o1 = f2bf((v1-mu)*rs*s[c+1]+b[c+1]);
  u16 o2 = f2bf((v2-mu)*rs*s[c+2]+b[c+2]);
  u16 o3 = f2bf((v3-mu)*rs*s[c+3]+b[c+3]);
  uint2 wv;
  wv.x = (unsigned)o0 | ((unsigned)o1 << 16);
  wv.y = (unsigned)o2 | ((unsigned)o3 << 16);
  *(uint2*)(xr + t * 4) = wv;
}

// ---------- FUSED 3-layer event transformer (r19-exact: packed weights + setprio)
__global__ __launch_bounds__(512, 1) void evt_fused(
    u16* __restrict__ se,
    const u16* __restrict__ attnWP, const float* __restrict__ attnB,
    const u16* __restrict__ f1P, const float* __restrict__ f1B,
    const u16* __restrict__ f2P, const float* __restrict__ f2B,
    const float* __restrict__ lnS, const float* __restrict__ lnB)
{
  __shared__ u16 X[32*264];
  __shared__ u16 Yb[2*32*264];
  __shared__ u16 Sb[8*32*40];
  __shared__ float st1[32*8], st2[32*8];
  __shared__ float muA[32], rsA[32];

  const int b = blockIdx.x;
  const int tid = threadIdx.x, w = tid >> 6, l = tid & 63;
  const int fr = l & 15, hi4 = (l >> 4) * 4, ko = (l >> 4) * 8;
  const long tb = (long)b * NTOKE;
  u16* Sw = Sb + w * 1280;
  u16* Y = Yb;

  for (int idx = tid; idx < 736; idx += 512){
    const int row = idx >> 5, c8 = (idx & 31) * 8;
    *(uint4*)&X[row*264 + c8] = *(const uint4*)(se + (tb + row)*256 + c8);
  }
  for (int idx = tid; idx < 288; idx += 512){
    const int row = 23 + (idx >> 5), c8 = (idx & 31) * 8;
    uint4 z = {0,0,0,0};
    *(uint4*)&X[row*264 + c8] = z;
  }
  __syncthreads();

  for (int lay = 0; lay < 3; lay++){
    const u16*  WlP = attnWP + (long)lay * 4 * 65536;
    const float* Bl = attnB + lay * 1024;
    const u16*  F1  = f1P + (long)lay * 524288;
    const u16*  F2  = f2P + (long)lay * 524288;

    bf16v8 qf[2], kf[2], pa[2];
    {
      bf16v8 wr_[8][2];
      #pragma unroll
      for (int ks = 0; ks < 8; ks++)
        #pragma unroll
        for (int ct = 0; ct < 2; ct++)
          wr_[ks][ct] = __builtin_bit_cast(bf16v8, *(const uint4*)(WlP + ((w*2+ct)*8 + ks)*512 + l*8));
      f32x4 acc[2][2] = {};
      __builtin_amdgcn_s_setprio(1);
      #pragma unroll
      for (int ks = 0; ks < 8; ks++){
        bf16v8 a0 = __builtin_bit_cast(bf16v8, *(const uint4*)&X[fr*264 + ks*32 + ko]);
        bf16v8 a1 = __builtin_bit_cast(bf16v8, *(const uint4*)&X[(16+fr)*264 + ks*32 + ko]);
        #pragma unroll
        for (int ct = 0; ct < 2; ct++){
          acc[0][ct] = __builtin_amdgcn_mfma_f32_16x16x32_bf16(a0, wr_[ks][ct], acc[0][ct], 0, 0, 0);
          acc[1][ct] = __builtin_amdgcn_mfma_f32_16x16x32_bf16(a1, wr_[ks][ct], acc[1][ct], 0, 0, 0);
        }
      }
      __builtin_amdgcn_s_setprio(0);
      #pragma unroll
      for (int rt = 0; rt < 2; rt++)
        #pragma unroll
        for (int ct = 0; ct < 2; ct++){
          const float bb = Bl[w*32 + ct*16 + fr];
          #pragma unroll
          for (int j = 0; j < 4; j++)
            Sw[(rt*16 + hi4 + j)*40 + ct*16 + fr] = f2bf(acc[rt][ct][j] + bb);
        }
      qf[0] = __builtin_bit_cast(bf16v8, *(const uint4*)&Sw[fr*40 + ko]);
      qf[1] = __builtin_bit_cast(bf16v8, *(const uint4*)&Sw[(16+fr)*40 + ko]);
    }
    {
      bf16v8 wr_[8][2];
      #pragma unroll
      for (int ks = 0; ks < 8; ks++)
        #pragma unroll
        for (int ct = 0; ct < 2; ct++)
          wr_[ks][ct] = __builtin_bit_cast(bf16v8, *(const uint4*)(WlP + 65536 + ((w*2+ct)*8 + ks)*512 + l*8));
      f32x4 acc[2][2] = {};
      __builtin_amdgcn_s_setprio(1);
      #pragma unroll
      for (int ks = 0; ks < 8; ks++){
        bf16v8 a0 = __builtin_bit_cast(bf16v8, *(const uint4*)&X[fr*264 + ks*32 + ko]);
        bf16v8 a1 = __builtin_bit_cast(bf16v8, *(const uint4*)&X[(16+fr)*264 + ks*32 + ko]);
        #pragma unroll
        for (int ct = 0; ct < 2; ct++){
          acc[0][ct] = __builtin_amdgcn_mfma_f32_16x16x32_bf16(a0, wr_[ks][ct], acc[0][ct], 0, 0, 0);
          acc[1][ct] = __builtin_amdgcn_mfma_f32_16x16x32_bf16(a1, wr_[ks][ct], acc[1][ct], 0, 0, 0);
        }
      }
      __builtin_amdgcn_s_setprio(0);
      #pragma unroll
      for (int rt = 0; rt < 2; rt++)
        #pragma unroll
        for (int ct = 0; ct < 2; ct++){
          const float bb = Bl[256 + w*32 + ct*16 + fr];
          #pragma unroll
          for (int j = 0; j < 4; j++)
            Sw[(rt*16 + hi4 + j)*40 + ct*16 + fr] = f2bf(acc[rt][ct][j] + bb);
        }
      kf[0] = __builtin_bit_cast(bf16v8, *(const uint4*)&Sw[fr*40 + ko]);
      kf[1] = __builtin_bit_cast(bf16v8, *(const uint4*)&Sw[(16+fr)*40 + ko]);
    }
    {
      f32x4 accS[2][2];
      #pragma unroll
      for (int rt = 0; rt < 2; rt++)
        #pragma unroll
        for (int nt = 0; nt < 2; nt++){
          f32x4 z = {0.f,0.f,0.f,0.f};
          accS[rt][nt] = __builtin_amdgcn_mfma_f32_16x16x32_bf16(qf[rt], kf[nt], z, 0, 0, 0);
        }
      const float SCALE = 0.17677669529663687f;
      const bool v1 = (fr < 7);
      #pragma unroll
      for (int rt = 0; rt < 2; rt++){
        #pragma unroll
        for (int j = 0; j < 4; j++){
          float x0 = accS[rt][0][j] * SCALE;
          float x1 = v1 ? accS[rt][1][j] * SCALE : -1e30f;
          float mx = fmaxf(x0, x1);
          #pragma unroll
          for (int o = 1; o < 16; o <<= 1) mx = fmaxf(mx, __shfl_xor(mx, o));
          float e0 = __expf(x0 - mx);
          float e1 = v1 ? __expf(x1 - mx) : 0.0f;
          float sum = e0 + e1;
          #pragma unroll
          for (int o = 1; o < 16; o <<= 1) sum += __shfl_xor(sum, o);
          const float inv = 1.0f / sum;
          const int row = rt*16 + hi4 + j;
          Sw[row*40 + fr]      = f2bf(e0 * inv);
          Sw[row*40 + 16 + fr] = f2bf(e1 * inv);
        }
      }
      pa[0] = __builtin_bit_cast(bf16v8, *(const uint4*)&Sw[fr*40 + ko]);
      pa[1] = __builtin_bit_cast(bf16v8, *(const uint4*)&Sw[(16+fr)*40 + ko]);
    }
    {
      bf16v8 wr_[8][2];
      #pragma unroll
      for (int ks = 0; ks < 8; ks++)
        #pragma unroll
        for (int ct = 0; ct < 2; ct++)
          wr_[ks][ct] = __builtin_bit_cast(bf16v8, *(const uint4*)(WlP + 131072 + ((w*2+ct)*8 + ks)*512 + l*8));
      f32x4 acc[2][2] = {};
      __builtin_amdgcn_s_setprio(1);
      #pragma unroll
      for (int ks = 0; ks < 8; ks++){
        bf16v8 a0 = __builtin_bit_cast(bf16v8, *(const uint4*)&X[fr*264 + ks*32 + ko]);
        bf16v8 a1 = __builtin_bit_cast(bf16v8, *(const uint4*)&X[(16+fr)*264 + ks*32 + ko]);
        #pragma unroll
        for (int ct = 0; ct < 2; ct++){
          acc[0][ct] = __builtin_amdgcn_mfma_f32_16x16x32_bf16(a0, wr_[ks][ct], acc[0][ct], 0, 0, 0);
          acc[1][ct] = __builtin_amdgcn_mfma_f32_16x16x32_bf16(a1, wr_[ks][ct], acc[1][ct], 0, 0, 0);
        }
      }
      __builtin_amdgcn_s_setprio(0);
      #pragma unroll
      for (int rt = 0; rt < 2; rt++)
        #pragma unroll
        for (int ct = 0; ct < 2; ct++){
          const float bb = Bl[512 + w*32 + ct*16 + fr];
          u16* dst = &Sw[(ct*16 + fr)*40 + rt*16 + hi4];
          #pragma unroll
          for (int j = 0; j < 4; j++)
            dst[j] = f2bf(acc[rt][ct][j] + bb);
        }
      bf16v8 vb0 = __builtin_bit_cast(bf16v8, *(const uint4*)&Sw[fr*40 + ko]);
      bf16v8 vb1 = __builtin_bit_cast(bf16v8, *(const uint4*)&Sw[(16+fr)*40 + ko]);
      f32x4 accO[2][2];
      #pragma unroll
      for (int rt = 0; rt < 2; rt++){
        f32x4 z = {0.f,0.f,0.f,0.f};
        accO[rt][0] = __builtin_amdgcn_mfma_f32_16x16x32_bf16(pa[rt], vb0, z, 0, 0, 0);
        accO[rt][1] = __builtin_amdgcn_mfma_f32_16x16x32_bf16(pa[rt], vb1, z, 0, 0, 0);
      }
      #pragma unroll
      for (int rt = 0; rt < 2; rt++)
        #pragma unroll
        for (int nt = 0; nt < 2; nt++)
          #pragma unroll
          for (int j = 0; j < 4; j++)
            Y[(rt*16 + hi4 + j)*264 + w*32 + nt*16 + fr] = f2bf(accO[rt][nt][j]);
    }
    __syncthreads();

    {
      bf16v8 wr_[8][2];
      #pragma unroll
      for (int ks = 0; ks < 8; ks++)
        #pragma unroll
        for (int ct = 0; ct < 2; ct++)
          wr_[ks][ct] = __builtin_bit_cast(bf16v8, *(const uint4*)(WlP + 196608 + ((w*2+ct)*8 + ks)*512 + l*8));
      f32x4 acc[2][2] = {};
      __builtin_amdgcn_s_setprio(1);
      #pragma unroll
      for (int ks = 0; ks < 8; ks++){
        bf16v8 a0 = __builtin_bit_cast(bf16v8, *(const uint4*)&Y[fr*264 + ks*32 + ko]);
        bf16v8 a1 = __builtin_bit_cast(bf16v8, *(const uint4*)&Y[(16+fr)*264 + ks*32 + ko]);
        #pragma unroll
        for (int ct = 0; ct < 2; ct++){
          acc[0][ct] = __builtin_amdgcn_mfma_f32_16x16x32_bf16(a0, wr_[ks][ct], acc[0][ct], 0, 0, 0);
          acc[1][ct] = __builtin_amdgcn_mfma_f32_16x16x32_bf16(a1, wr_[ks][ct], acc[1][ct], 0, 0, 0);
        }
      }
      __builtin_amdgcn_s_setprio(0);
      float val[2][2][4];
      #pragma unroll
      for (int ct = 0; ct < 2; ct++){
        const int col = w*32 + ct*16 + fr;
        const float bb = Bl[768 + col];
        #pragma unroll
        for (int rt = 0; rt < 2; rt++)
          #pragma unroll
          for (int j = 0; j < 4; j++)
            val[rt][ct][j] = acc[rt][ct][j] + bb + bf2f(X[(rt*16 + hi4 + j)*264 + col]);
      }
      #pragma unroll
      for (int rt = 0; rt < 2; rt++)
        #pragma unroll
        for (int j = 0; j < 4; j++){
          float s1 = val[rt][0][j] + val[rt][1][j];
          float s2 = val[rt][0][j]*val[rt][0][j] + val[rt][1][j]*val[rt][1][j];
          #pragma unroll
          for (int o = 1; o < 16; o <<= 1){ s1 += __shfl_xor(s1, o); s2 += __shfl_xor(s2, o); }
          if (fr == 0){
            const int row = rt*16 + hi4 + j;
            st1[row*8 + w] = s1; st2[row*8 + w] = s2;
          }
        }
      __syncthreads();
      if (tid < 32){
        float s1 = 0.f, s2 = 0.f;
        #pragma unroll
        for (int k = 0; k < 8; k++){ s1 += st1[tid*8 + k]; s2 += st2[tid*8 + k]; }
        const float mu = s1 * (1.0f/256.0f);
        const float var = s2 * (1.0f/256.0f) - mu*mu;
        muA[tid] = mu; rsA[tid] = rsqrtf(var + 1e-5f);
      }
      __syncthreads();
      #pragma unroll
      for (int ct = 0; ct < 2; ct++){
        const int col = w*32 + ct*16 + fr;
        const float lw = lnS[lay*512 + col], lb = lnB[lay*512 + col];
        #pragma unroll
        for (int rt = 0; rt < 2; rt++)
          #pragma unroll
          for (int j = 0; j < 4; j++){
            const int row = rt*16 + hi4 + j;
            X[row*264 + col] = f2bf((val[rt][ct][j] - muA[row]) * rsA[row] * lw + lb);
          }
      }
      __syncthreads();
    }

    {
      f32x4 acc2[2][2] = {};
      for (int c = 0; c < 8; c++){
        u16* Yc = Yb + (c & 1) * 8448;
        bf16v8 w1r[8][2];
        #pragma unroll
        for (int ks = 0; ks < 8; ks++)
          #pragma unroll
          for (int ct = 0; ct < 2; ct++)
            w1r[ks][ct] = __builtin_bit_cast(bf16v8, *(const uint4*)(F1 + (long)((c*16 + w*2 + ct)*8 + ks)*512 + l*8));
        f32x4 acc1[2][2] = {};
        __builtin_amdgcn_s_setprio(1);
        #pragma unroll
        for (int ks = 0; ks < 8; ks++){
          bf16v8 a0 = __builtin_bit_cast(bf16v8, *(const uint4*)&X[fr*264 + ks*32 + ko]);
          bf16v8 a1 = __builtin_bit_cast(bf16v8, *(const uint4*)&X[(16+fr)*264 + ks*32 + ko]);
          #pragma unroll
          for (int ct = 0; ct < 2; ct++){
            acc1[0][ct] = __builtin_amdgcn_mfma_f32_16x16x32_bf16(a0, w1r[ks][ct], acc1[0][ct], 0, 0, 0);
            acc1[1][ct] = __builtin_amdgcn_mfma_f32_16x16x32_bf16(a1, w1r[ks][ct], acc1[1][ct], 0, 0, 0);
          }
        }
        __builtin_amdgcn_s_setprio(0);
        bf16v8 w2r[8][2];
        #pragma unroll
        for (int ks = 0; ks < 8; ks++)
          #pragma unroll
          for (int ct = 0; ct < 2; ct++)
            w2r[ks][ct] = __builtin_bit_cast(bf16v8, *(const uint4*)(F2 + (long)((w*2+ct)*64 + c*8 + ks)*512 + l*8));
        #pragma unroll
        for (int ct = 0; ct < 2; ct++){
          const float bb = f1B[lay*2048 + c*256 + w*32 + ct*16 + fr];
          #pragma unroll
          for (int rt = 0; rt < 2; rt++)
            #pragma unroll
            for (int j = 0; j < 4; j++)
              Yc[(rt*16 + hi4 + j)*264 + w*32 + ct*16 + fr] = f2bf(fmaxf(acc1[rt][ct][j] + bb, 0.0f));
        }
        __syncthreads();
        __builtin_amdgcn_s_setprio(1);
        #pragma unroll
        for (int ks = 0; ks < 8; ks++){
          bf16v8 a0 = __builtin_bit_cast(bf16v8, *(const uint4*)&Yc[fr*264 + ks*32 + ko]);
          bf16v8 a1 = __builtin_bit_cast(bf16v8, *(const uint4*)&Yc[(16+fr)*264 + ks*32 + ko]);
          #pragma unroll
          for (int ct = 0; ct < 2; ct++){
            acc2[0][ct] = __builtin_amdgcn_mfma_f32_16x16x32_bf16(a0, w2r[ks][ct], acc2[0][ct], 0, 0, 0);
            acc2[1][ct] = __builtin_amdgcn_mfma_f32_16x16x32_bf16(a1, w2r[ks][ct], acc2[1][ct], 0, 0, 0);
          }
        }
        __builtin_amdgcn_s_setprio(0);
      }
      __syncthreads();
      float val[2][2][4];
      #pragma unroll
      for (int ct = 0; ct < 2; ct++){
        const int col = w*32 + ct*16 + fr;
        const float bb = f2B[lay*256 + col];
        #pragma unroll
        for (int rt = 0; rt < 2; rt++)
          #pragma unroll
          for (int j = 0; j < 4; j++)
            val[rt][ct][j] = acc2[rt][ct][j] + bb + bf2f(X[(rt*16 + hi4 + j)*264 + col]);
      }
      #pragma unroll
      for (int rt = 0; rt < 2; rt++)
        #pragma unroll
        for (int j = 0; j < 4; j++){
          float s1 = val[rt][0][j] + val[rt][1][j];
          float s2 = val[rt][0][j]*val[rt][0][j] + val[rt][1][j]*val[rt][1][j];
          #pragma unroll
          for (int o = 1; o < 16; o <<= 1){ s1 += __shfl_xor(s1, o); s2 += __shfl_xor(s2, o); }
          if (fr == 0){
            const int row = rt*16 + hi4 + j;
            st1[row*8 + w] = s1; st2[row*8 + w] = s2;
          }
        }
      __syncthreads();
      if (tid < 32){
        float s1 = 0.f, s2 = 0.f;
        #pragma unroll
        for (int k = 0; k < 8; k++){ s1 += st1[tid*8 + k]; s2 += st2[tid*8 + k]; }
        const float mu = s1 * (1.0f/256.0f);
        const float var = s2 * (1.0f/256.0f) - mu*mu;
        muA[tid] = mu; rsA[tid] = rsqrtf(var + 1e-5f);
      }
      __syncthreads();
      #pragma unroll
      for (int ct = 0; ct < 2; ct++){
        const int col = w*32 + ct*16 + fr;
        const float lw = lnS[lay*512 + 256 + col], lb = lnB[lay*512 + 256 + col];
        #pragma unroll
        for (int rt = 0; rt < 2; rt++)
          #pragma unroll
          for (int j = 0; j < 4; j++){
            const int row = rt*16 + hi4 + j;
            X[row*264 + col] = f2bf((val[rt][ct][j] - muA[row]) * rsA[row] * lw + lb);
          }
      }
      __syncthreads();
    }
  }

  for (int idx = tid; idx < 736; idx += 512){
    const int row = idx >> 5, c8 = (idx & 31) * 8;
    *(uint4*)(se + (tb + row)*256 + c8) = *(const uint4*)&X[row*264 + c8];
  }
}

// ---------- glob MLP stage 1
__global__ __launch_bounds__(256) void glob1_k(const float* __restrict__ xg, const float* __restrict__ w1,
                                               const float* __restrict__ b1, u16* __restrict__ h){
  int b = blockIdx.x, d = threadIdx.x;
  float s = b1[d];
  #pragma unroll
  for (int k = 0; k < 16; k++) s += xg[b*16 + k] * w1[k*256 + d];
  h[(long)b*256 + d] = f2bf(gelu_fast(s));
}

// ---------- event sequence fill
__global__ __launch_bounds__(64) void fill_se(u16* __restrict__ se, const float* __restrict__ cls_task,
                                              const u16* __restrict__ globo, const float* __restrict__ pos_emb,
                                              const float* __restrict__ empty_emb){
  int bt = blockIdx.x;
  int b = bt / NTOKE, tk = bt % NTOKE;
  int t = threadIdx.x;
  u16* d = se + (long)bt * D_MOD;
  #pragma unroll
  for (int j = 0; j < 4; j++){
    int c = t*4 + j;
    float v;
    if (tk < 7) v = cls_task[tk*D_MOD + c];
    else if (tk == 7) v = bf2f(globo[(long)b*D_MOD + c]) + pos_emb[c];
    else v = empty_emb[c] + pos_emb[(tk - 7)*D_MOD + c];
    d[c] = f2bf(v);
  }
}

// ---------- scatter module CLS into event sequence (+pos_emb)
__global__ __launch_bounds__(64) void scatter_mod(u16* __restrict__ se, const u16* __restrict__ seqc,
                                                  const int* __restrict__ m2e, const int* __restrict__ mpos,
                                                  const int* __restrict__ starts,
                                                  const float* __restrict__ pos_emb){
  int m = blockIdx.x, t = threadIdx.x;
  int e = m2e[m], p = mpos[m];
  const u16* src = seqc + ((long)starts[m] + m) * D_MOD;
  u16* dst = se + ((long)e * NTOKE + 8 + p) * D_MOD;
  const float* pe = pos_emb + (long)(1 + p) * D_MOD;
  #pragma unroll
  for (int j = 0; j < 4; j++){
    int c = t*4 + j;
    dst[c] = f2bf(bf2f(src[c]) + pe[c]);
  }
}

// ---------- heads
__global__ __launch_bounds__(64) void heads_k(const u16* __restrict__ se, const float* __restrict__ hw,
                                              const float* __restrict__ hb, float* __restrict__ out){
  int b = blockIdx.x, t = threadIdx.x;
  __shared__ float raw[16];
  if (t < 16){
    int tok = (t < 4) ? 0 : (t <= 8) ? (t - 3) : (t <= 11) ? 5 : 6;
    const u16* e = se + ((long)b * NTOKE + tok) * D_MOD;
    float s = hb[t];
    for (int d = 0; d < 256; d++) s += bf2f(e[d]) * hw[d*16 + t];
    raw[t] = s;
  }
  __syncthreads();
  if (t < 16){
    float v = raw[t];
    float r;
    if (t <= 8 || t == 12){
      r = fmaxf(v, 0.0f) + log1pf(__expf(-fabsf(v)));
    } else if (t <= 11){
      float n = sqrtf(raw[9]*raw[9] + raw[10]*raw[10] + raw[11]*raw[11]);
      r = v / fmaxf(n, 1e-12f);
    } else {
      float n = sqrtf(raw[13]*raw[13] + raw[14]*raw[14] + raw[15]*raw[15]);
      r = v / fmaxf(n, 1e-12f);
    }
    out[b*16 + t] = r;
  }
}

extern "C" void kernel_launch(void* const* d_in, const int* in_sizes, int n_in,
                              void* d_out, int out_size, void* d_ws, size_t ws_size,
                              hipStream_t stream){
  const float* feats      = (const float*)d_in[0];
  const float* coords     = (const float*)d_in[1];
  const int*   batch_ids  = (const int*)d_in[2];
  const int*   m2e        = (const int*)d_in[3];
  const int*   mpos       = (const int*)d_in[4];
  const float* x_glob     = (const float*)d_in[5];
  const float* cls_mod    = (const float*)d_in[6];
  const float* empty_emb  = (const float*)d_in[7];
  const float* cls_task   = (const float*)d_in[8];
  const float* pos_emb    = (const float*)d_in[9];
  const float* mod_attn_w = (const float*)d_in[10];
  const float* mod_attn_b = (const float*)d_in[11];
  const float* mod_rel    = (const float*)d_in[12];
  const float* mod_ln_s   = (const float*)d_in[13];
  const float* mod_ln_b   = (const float*)d_in[14];
  const float* mod_ffn_w1 = (const float*)d_in[15];
  const float* mod_ffn_b1 = (const float*)d_in[16];
  const float* mod_ffn_w2 = (const float*)d_in[17];
  const float* mod_ffn_b2 = (const float*)d_in[18];
  const float* glob_w1    = (const float*)d_in[19];
  const float* glob_b1    = (const float*)d_in[20];
  const float* glob_w2    = (const float*)d_in[21];
  const float* glob_b2    = (const float*)d_in[22];
  const float* evt_attn_w = (const float*)d_in[23];
  const float* evt_attn_b = (const float*)d_in[24];
  const float* evt_ln_s   = (const float*)d_in[25];
  const float* evt_ln_b   = (const float*)d_in[26];
  const float* evt_ffn_w1 = (const float*)d_in[27];
  const float* evt_ffn_b1 = (const float*)d_in[28];
  const float* evt_ffn_w2 = (const float*)d_in[29];
  const float* evt_ffn_b2 = (const float*)d_in[30];
  const float* head_w     = (const float*)d_in[31];
  const float* head_b     = (const float*)d_in[32];
  float* out = (float*)d_out;

  const int N = in_sizes[0] / 256;
  const int M = in_sizes[3];
  const int B = in_sizes[5] / 16;
  const long CROWS   = (long)M + N;                         // 54306
  const long CROWS_P = (((CROWS + 255) >> 8) << 8) + 256;   // pad to x256 + overrun guard
  const long TE  = (long)B * NTOKE;

  char* ws = (char*)d_ws;
  u16* modWT   = (u16*)ws;
  u16* evtWT   = modWT + 8L*65536;
  u16* modF1T  = evtWT + 12L*65536;
  u16* modF2T  = modF1T + 2L*262144;
  u16* evtF1T  = modF2T + 2L*262144;
  u16* evtF2T  = evtF1T + 3L*524288;
  u16* globW2T = evtF2T + 3L*524288;
  size_t off = 11468800;
  int* counts = (int*)(ws + off); off += 16*1024;
  int* starts = (int*)(ws + off); off += 16*1024;
  float* scc  = (float*)(ws + off); off += ((size_t)CROWS_P*12 + 255) & ~(size_t)255;
  u16* seqc   = (u16*)(ws + off); off += (size_t)CROWS_P * D_MOD * 2;
  off = (off + 255) & ~(size_t)255;
  const size_t OFF_BIG = off;
  u16* qkv   = (u16*)(ws + OFF_BIG);
  u16* attno = (u16*)(ws + OFF_BIG + (size_t)CROWS_P*768*2);
  u16* ffh   = (u16*)(ws + OFF_BIG);
  u16* se    = (u16*)(ws + OFF_BIG);
  u16* globh = (u16*)(ws + OFF_BIG + 12*1024*1024);
  u16* globo = (u16*)(ws + OFF_BIG + 13*1024*1024);
  u16* evtWP  = (u16*)(ws + OFF_BIG + 120L*1024*1024);
  u16* evtF1P = evtWP + 12L*65536;
  u16* evtF2P = evtF1P + 3L*524288;

  prep_all<<<5440, 256, 0, stream>>>(mod_attn_w, evt_attn_w, mod_ffn_w1, mod_ffn_w2,
                                     evt_ffn_w1, evt_ffn_w2, glob_w2,
                                     modWT, evtWT, modF1T, modF2T, evtF1T, evtF2T, globW2T,
                                     evtWP, evtF1P, evtF2P);

  hipMemsetAsync(counts, 0, (size_t)M*4, stream);
  hipMemsetAsync(scc, 0, (size_t)CROWS_P*12, stream);
  hipMemsetAsync(seqc + CROWS*D_MOD, 0, (size_t)(CROWS_P - CROWS)*D_MOD*2, stream);
  count_k<<<(N + 255)/256, 256, 0, stream>>>(batch_ids, counts, N);
  scan_k<<<1, 1024, 0, stream>>>(counts, starts, M);
  cls_fill<<<M, 64, 0, stream>>>(seqc, cls_mod, starts);
  scatter_k<<<N, 64, 0, stream>>>(feats, coords, batch_ids, seqc, scc);

  const int RB = (int)(CROWS_P / 256);
  for (int l = 0; l < 2; l++){
    gemm256<0><<<dim3(6, RB), 512, 0, stream>>>(seqc, modWT + (long)l*4*65536,
        mod_attn_b + l*1024, nullptr, qkv, 256, 768);
    mod_attn_all<<<dim3(M, NHEAD), 256, 0, stream>>>(qkv, scc, mod_rel + l*24, counts, starts, attno);
    gemm256<3><<<dim3(2, RB), 512, 0, stream>>>(attno, modWT + ((long)l*4+3)*65536,
        mod_attn_b + l*1024 + 768, seqc, seqc, 256, 256);
    ln_k<<<(int)((CROWS + 3)/4), 256, 0, stream>>>(seqc, mod_ln_s + (l*2)*256, mod_ln_b + (l*2)*256, CROWS);
    gemm256<1><<<dim3(8, RB), 512, 0, stream>>>(seqc, modF1T + (long)l*262144,
        mod_ffn_b1 + l*1024, nullptr, ffh, 256, 1024);
    gemm256<3><<<dim3(2, RB), 512, 0, stream>>>(ffh, modF2T + (long)l*262144,
        mod_ffn_b2 + l*256, seqc, seqc, 1024, 256);
    ln_k<<<(int)((CROWS + 3)/4), 256, 0, stream>>>(seqc, mod_ln_s + (l*2+1)*256, mod_ln_b + (l*2+1)*256, CROWS);
  }

  hipMemsetAsync(globh, 0, 256*256*2, stream);
  glob1_k<<<B, 256, 0, stream>>>(x_glob, glob_w1, glob_b1, globh);
  gemm256<0><<<dim3(2, 1), 512, 0, stream>>>(globh, globW2T, glob_b2, nullptr, globo, 256, 256);
  fill_se<<<(int)TE, 64, 0, stream>>>(se, cls_task, globo, pos_emb, empty_emb);
  scatter_mod<<<M, 64, 0, stream>>>(se, seqc, m2e, mpos, starts, pos_emb);

  evt_fused<<<B, 512, 0, stream>>>(se, evtWP, evt_attn_b, evtF1P, evt_ffn_b1,
                                   evtF2P, evt_ffn_b2, evt_ln_s, evt_ln_b);

  heads_k<<<B, 64, 0, stream>>>(se, head_w, head_b, out);
}